// Round 1
// baseline (1590.536 us; speedup 1.0000x reference)
//
#include <hip/hip_runtime.h>

typedef unsigned short u16;
typedef __attribute__((ext_vector_type(8))) _Float16 f16x8;
typedef __attribute__((ext_vector_type(4))) float f32x4;

#define DEVINL __device__ __forceinline__

DEVINL u16 f2h_u(float f) {
    _Float16 h = (_Float16)f;
    return __builtin_bit_cast(unsigned short, h);
}

DEVINL f16x8 ldfrag(const u16* p) {
    union { int2 d[2]; f16x8 v; } u;
    u.d[0] = *(const int2*)(p);
    u.d[1] = *(const int2*)(p + 4);
    return u.v;
}

// ---------------------------------------------------------------------------
// NT GEMM: C[i,j] = sum_k A[i,k]*B[j,k], fp16 operands, f32 accum.
// BM=BN=128, BK=32, 256 threads = 4 waves in 2x2, each wave 64x64 (4x4 frags).
// EPI: 0 = fp16 store + bias[col];  1 = f32 store;  2 = atomicAdd f32 (split-K);
//      3 = f32 store of gamma*acc + src[row,col]  (src may alias out)
// z-dim: batch (strides) when splitK==0, else K-slice index.
// ---------------------------------------------------------------------------
template<int EPI>
__launch_bounds__(256)
__global__ void gemm_nt(const u16* __restrict__ A, int lda, long sAz,
                        const u16* __restrict__ B, int ldb, long sBz,
                        int K, int splitK,
                        const float* __restrict__ bias,
                        const float* gptr,
                        const float* src, long sSz, int ldsrc,
                        void* outv, int ldo, long sOz)
{
    __shared__ u16 As[128 * 40];   // pad 32->40: 8B-aligned frag reads, <=2-way banks
    __shared__ u16 Bs[128 * 40];

    int z = blockIdx.z;
    int kOff, kLen;
    long zo = 0, zs = 0;
    if (splitK > 0) { kOff = z * splitK; kLen = splitK; }
    else { kOff = 0; kLen = K; A += sAz * z; B += sBz * z; zo = sOz * z; zs = sSz * z; }

    int tid = threadIdx.x;
    int lane = tid & 63, w = tid >> 6;
    int wr = w >> 1, wc = w & 1;
    int rowBase = blockIdx.y * 128, colBase = blockIdx.x * 128;
    const u16* Ag = A + (size_t)rowBase * lda + kOff;
    const u16* Bg = B + (size_t)colBase * ldb + kOff;
    int kg = lane >> 4, rl = lane & 15;

    f32x4 zf = {0.f, 0.f, 0.f, 0.f};
    f32x4 acc[4][4];
#pragma unroll
    for (int i = 0; i < 4; ++i)
#pragma unroll
        for (int j = 0; j < 4; ++j) acc[i][j] = zf;

    int r0 = tid >> 2;            // 0..63
    int kk0 = (tid & 3) * 8;      // 0,8,16,24

    for (int k0 = 0; k0 < kLen; k0 += 32) {
        __syncthreads();
#pragma unroll
        for (int p = 0; p < 2; ++p) {
            int r = p * 64 + r0;
            int4 va = *(const int4*)(Ag + (size_t)r * lda + k0 + kk0);
            int4 vb = *(const int4*)(Bg + (size_t)r * ldb + k0 + kk0);
            u16* pa = &As[r * 40 + kk0];
            ((int2*)pa)[0] = make_int2(va.x, va.y);
            *(int2*)(pa + 4) = make_int2(va.z, va.w);
            u16* pb = &Bs[r * 40 + kk0];
            ((int2*)pb)[0] = make_int2(vb.x, vb.y);
            *(int2*)(pb + 4) = make_int2(vb.z, vb.w);
        }
        __syncthreads();
        f16x8 af[4], bfr[4];
#pragma unroll
        for (int i = 0; i < 4; ++i) {
            af[i]  = ldfrag(&As[(wr * 64 + i * 16 + rl) * 40 + kg * 8]);
            bfr[i] = ldfrag(&Bs[(wc * 64 + i * 16 + rl) * 40 + kg * 8]);
        }
#pragma unroll
        for (int i = 0; i < 4; ++i)
#pragma unroll
            for (int j = 0; j < 4; ++j)
                acc[i][j] = __builtin_amdgcn_mfma_f32_16x16x32_f16(af[i], bfr[j], acc[i][j], 0, 0, 0);
    }

    float gamma = 0.f;
    if (EPI == 3) gamma = *gptr;
    u16* outh = (u16*)outv;
    float* outf = (float*)outv;
#pragma unroll
    for (int i = 0; i < 4; ++i) {
        int row0 = rowBase + wr * 64 + i * 16 + kg * 4;
#pragma unroll
        for (int j = 0; j < 4; ++j) {
            int col = colBase + wc * 64 + j * 16 + rl;
            f32x4 v = acc[i][j];
#pragma unroll
            for (int r = 0; r < 4; ++r) {
                int row = row0 + r;
                size_t o = (size_t)row * ldo + col;
                if (EPI == 0) {
                    outh[zo + o] = f2h_u(v[r] + bias[col]);
                } else if (EPI == 1) {
                    outf[o] = v[r];
                } else if (EPI == 2) {
                    atomicAdd(&outf[o], v[r]);
                } else {
                    size_t os = (size_t)row * ldsrc + col;
                    outf[zo + o] = gamma * v[r] + src[zs + os];
                }
            }
        }
    }
}

// f32 [R][NC] -> fp16 [NC][R] transpose (64x64 LDS tiles)
__global__ void tr_f32_h(const float* __restrict__ in, u16* __restrict__ out,
                         int R, int NC_, long sIn, long sOut)
{
    in += (long)blockIdx.z * sIn; out += (long)blockIdx.z * sOut;
    __shared__ u16 s[64 * 65];
    int tx = threadIdx.x & 63, tw = threadIdx.x >> 6;
    int r0 = blockIdx.y * 64, c0 = blockIdx.x * 64;
#pragma unroll
    for (int p = 0; p < 16; ++p) {
        int r = tw + p * 4;
        s[tx * 65 + r] = f2h_u(in[(size_t)(r0 + r) * NC_ + c0 + tx]);
    }
    __syncthreads();
#pragma unroll
    for (int p = 0; p < 16; ++p) {
        int rr = tw + p * 4;
        out[(size_t)(c0 + rr) * R + r0 + tx] = s[rr * 65 + tx];
    }
}

// fp16 [R][NC] -> fp16 [NC][R]
__global__ void tr_h_h(const u16* __restrict__ in, u16* __restrict__ out,
                       int R, int NC_, long sIn, long sOut)
{
    in += (long)blockIdx.z * sIn; out += (long)blockIdx.z * sOut;
    __shared__ u16 s[64 * 65];
    int tx = threadIdx.x & 63, tw = threadIdx.x >> 6;
    int r0 = blockIdx.y * 64, c0 = blockIdx.x * 64;
#pragma unroll
    for (int p = 0; p < 16; ++p) {
        int r = tw + p * 4;
        s[tx * 65 + r] = in[(size_t)(r0 + r) * NC_ + c0 + tx];
    }
    __syncthreads();
#pragma unroll
    for (int p = 0; p < 16; ++p) {
        int rr = tw + p * 4;
        out[(size_t)(c0 + rr) * R + r0 + tx] = s[rr * 65 + tx];
    }
}

__global__ void cvt_w_kernel(const float* __restrict__ w0, const float* __restrict__ w1,
                             const float* __restrict__ w2, const float* __restrict__ w3,
                             u16* __restrict__ out)
{
    int i = blockIdx.x * 256 + threadIdx.x;
    const float* w = (i < 65536) ? w0 : (i < 131072) ? w1 : (i < 196608) ? w2 : w3;
    out[i] = f2h_u(w[i & 65535]);
}

// column-wise (over m) online max/sum-exp partials of St[4096][4096]
__global__ void colstats_partial(const float* __restrict__ St,
                                 float* __restrict__ pmax, float* __restrict__ psum)
{
    int col = blockIdx.x * 256 + threadIdx.x;
    int m0 = blockIdx.y * 256;
    float mx = -3.0e38f, sm = 0.f;
    for (int m = 0; m < 256; ++m) {
        float v = St[(size_t)(m0 + m) * 4096 + col];
        if (v > mx) { sm = sm * __expf(mx - v) + 1.f; mx = v; }
        else sm += __expf(v - mx);
    }
    pmax[blockIdx.y * 4096 + col] = mx;
    psum[blockIdx.y * 4096 + col] = sm;
}

__global__ void colstats_combine(const float* __restrict__ pmax, const float* __restrict__ psum,
                                 float* __restrict__ cmax, float* __restrict__ crcp)
{
    int col = blockIdx.x * 256 + threadIdx.x;
    float mx = -3.0e38f;
    for (int i = 0; i < 16; ++i) mx = fmaxf(mx, pmax[i * 4096 + col]);
    float s = 0.f;
    for (int i = 0; i < 16; ++i) s += psum[i * 4096 + col] * __expf(pmax[i * 4096 + col] - mx);
    cmax[col] = mx;
    crcp[col] = 1.f / s;
}

// Pt[m,n] = fp16( exp(St[m,n]-cmax[n]) * crcp[n] )
__global__ void pt_kernel(const float* __restrict__ St, const float* __restrict__ cmax,
                          const float* __restrict__ crcp, u16* __restrict__ Pt)
{
    int m = blockIdx.y;
    int col = blockIdx.x * 256 + threadIdx.x;
    size_t o = (size_t)m * 4096 + col;
    Pt[o] = f2h_u(__expf(St[o] - cmax[col]) * crcp[col]);
}

DEVINL float blockReduce(float v, int op) {  // op 0 = max, 1 = sum; 256 threads
    __shared__ float s[4];
#pragma unroll
    for (int o = 32; o; o >>= 1) {
        float t = __shfl_xor(v, o, 64);
        v = op ? (v + t) : fmaxf(v, t);
    }
    __syncthreads();
    if ((threadIdx.x & 63) == 0) s[threadIdx.x >> 6] = v;
    __syncthreads();
    return op ? (s[0] + s[1] + s[2] + s[3]) : fmaxf(fmaxf(s[0], s[1]), fmaxf(s[2], s[3]));
}

// sim_c row softmax of (rowmax(E) - E) over d; E f32 [256][256]
__global__ void simc_kernel(const float* __restrict__ E, u16* __restrict__ simc)
{
    int c = blockIdx.x, d = threadIdx.x;
    float e = E[c * 256 + d];
    float rmax = blockReduce(e, 0);
    float v = rmax - e;
    float vmax = blockReduce(v, 0);
    float p = __expf(v - vmax);
    float s = blockReduce(p, 1);
    simc[c * 256 + d] = f2h_u(p / s);
}

extern "C" void kernel_launch(void* const* d_in, const int* in_sizes, int n_in,
                              void* d_out, int out_size, void* d_ws, size_t ws_size,
                              hipStream_t stream)
{
    const float* x      = (const float*)d_in[0];
    const float* xth    = (const float*)d_in[1];
    const float* Wk_rgb = (const float*)d_in[2];
    const float* bk_rgb = (const float*)d_in[3];
    const float* Wk_th  = (const float*)d_in[4];
    const float* bk_th  = (const float*)d_in[5];
    const float* Wv_rgb = (const float*)d_in[6];
    const float* bv_rgb = (const float*)d_in[7];
    const float* Wv_th  = (const float*)d_in[8];
    const float* bv_th  = (const float*)d_in[9];
    const float* g1r = (const float*)d_in[10];
    const float* g1t = (const float*)d_in[11];
    const float* g2r = (const float*)d_in[12];
    const float* g2t = (const float*)d_in[13];

    const long CN = 256L * 4096L;   // per-batch per-tensor elems

    // workspace carve-up (~169 MB)
    u16* wts  = (u16*)d_ws;           // [4][256][256] fp16 weights
    u16* xT   = wts + 4 * 65536;      // [4][4096][256] x^T
    u16* xthT = xT + 4 * CN;
    u16* Kt   = xthT + 4 * CN;        // x_k^T   [n][c]
    u16* Ktth = Kt + 4 * CN;          // x_th_k^T
    u16* Vt   = Ktth + 4 * CN;        // x_v^T
    u16* Vtht = Vt + 4 * CN;          // x_v_th^T
    u16* Vv   = Vtht + 4 * CN;        // x_v    [c][n]
    u16* Vth  = Vv + 4 * CN;          // x_v_th [c][n]
    u16* simc = Vth + 4 * CN;         // [256][256] fp16 (per-batch reuse)
    u16* Pt   = simc + 65536;         // [4096][4096] fp16 (per-batch reuse)
    float* St = (float*)(Pt + 4096L * 4096L);  // [4096][4096] f32 (per-batch reuse)
    float* pmax = St + 4096L * 4096L;
    float* psum = pmax + 16 * 4096;
    float* cmax = psum + 16 * 4096;
    float* crcp = cmax + 4096;
    float* E    = crcp + 4096;        // [256][256] f32

    float* outX2  = (float*)d_out;          // x_2   [4][256][4096]
    float* outXt2 = outX2 + 4 * CN;         // x_th_2

    cvt_w_kernel<<<1024, 256, 0, stream>>>(Wk_rgb, Wk_th, Wv_rgb, Wv_th, wts);
    tr_f32_h<<<dim3(64, 4, 4), 256, 0, stream>>>(x,   xT,   256, 4096, CN, CN);
    tr_f32_h<<<dim3(64, 4, 4), 256, 0, stream>>>(xth, xthT, 256, 4096, CN, CN);

    // projections -> [n][o] fp16 (batched over z)
    gemm_nt<0><<<dim3(2, 32, 4), 256, 0, stream>>>(xT,   256, CN, wts,          256, 0, 256, 0, bk_rgb, nullptr, nullptr, 0, 0, Kt,   256, CN);
    gemm_nt<0><<<dim3(2, 32, 4), 256, 0, stream>>>(xthT, 256, CN, wts + 65536,  256, 0, 256, 0, bk_th,  nullptr, nullptr, 0, 0, Ktth, 256, CN);
    gemm_nt<0><<<dim3(2, 32, 4), 256, 0, stream>>>(xT,   256, CN, wts + 131072, 256, 0, 256, 0, bv_rgb, nullptr, nullptr, 0, 0, Vt,   256, CN);
    gemm_nt<0><<<dim3(2, 32, 4), 256, 0, stream>>>(xthT, 256, CN, wts + 196608, 256, 0, 256, 0, bv_th,  nullptr, nullptr, 0, 0, Vtht, 256, CN);

    tr_h_h<<<dim3(4, 64, 4), 256, 0, stream>>>(Vt,   Vv,  4096, 256, CN, CN);
    tr_h_h<<<dim3(4, 64, 4), 256, 0, stream>>>(Vtht, Vth, 4096, 256, CN, CN);

    for (int b = 0; b < 4; ++b) {
        const u16* Ktb   = Kt   + b * CN;
        const u16* Ktthb = Ktth + b * CN;
        const u16* Vb    = Vv   + b * CN;
        const u16* Vthb  = Vth  + b * CN;
        const u16* Vtb   = Vt   + b * CN;
        const u16* Vthtb = Vtht + b * CN;

        // St[m,n] = sum_c x_k[m,c] * x_th_k[n,c]  ( = S[n,m] )
        gemm_nt<1><<<dim3(32, 32, 1), 256, 0, stream>>>(Ktb, 256, 0, Ktthb, 256, 0, 256, 0, nullptr, nullptr, nullptr, 0, 0, St, 4096, 0);
        colstats_partial<<<dim3(16, 16), 256, 0, stream>>>(St, pmax, psum);
        colstats_combine<<<16, 256, 0, stream>>>(pmax, psum, cmax, crcp);
        pt_kernel<<<dim3(16, 4096), 256, 0, stream>>>(St, cmax, crcp, Pt);

        // x_1 = gamma * (V @ P) + x   (staged into d_out)
        gemm_nt<3><<<dim3(32, 2, 1), 256, 0, stream>>>(Vb,   4096, 0, Pt, 4096, 0, 4096, 0, nullptr, g1r, x   + b * CN, 0, 4096, outX2  + b * CN, 4096, 0);
        gemm_nt<3><<<dim3(32, 2, 1), 256, 0, stream>>>(Vthb, 4096, 0, Pt, 4096, 0, 4096, 0, nullptr, g1t, xth + b * CN, 0, 4096, outXt2 + b * CN, 4096, 0);

        // energy[c,d] = sum_n Vth[c,n] V[d,n]  (split-K=128, 32 slices, atomics)
        (void)hipMemsetAsync(E, 0, 65536 * sizeof(float), stream);
        gemm_nt<2><<<dim3(2, 2, 32), 256, 0, stream>>>(Vthb, 4096, 0, Vb, 4096, 0, 4096, 128, nullptr, nullptr, nullptr, 0, 0, E, 256, 0);
        simc_kernel<<<256, 256, 0, stream>>>(E, simc);

        // x_2 = gamma2 * (simc @ V) + x_1   (reads+overwrites d_out in place)
        gemm_nt<3><<<dim3(32, 2, 1), 256, 0, stream>>>(simc, 256, 0, Vtb,   256, 0, 256, 0, nullptr, g2r, outX2  + b * CN, 0, 4096, outX2  + b * CN, 4096, 0);
        gemm_nt<3><<<dim3(32, 2, 1), 256, 0, stream>>>(simc, 256, 0, Vthtb, 256, 0, 256, 0, nullptr, g2t, outXt2 + b * CN, 0, 4096, outXt2 + b * CN, 4096, 0);
    }
}

// Round 2
// 749.600 us; speedup vs baseline: 2.1218x; 2.1218x over previous
//
#include <hip/hip_runtime.h>

typedef unsigned short u16;
typedef __attribute__((ext_vector_type(8))) _Float16 f16x8;
typedef __attribute__((ext_vector_type(4))) float f32x4;

#define DEVINL __device__ __forceinline__

DEVINL u16 f2h_u(float f) {
    _Float16 h = (_Float16)f;
    return __builtin_bit_cast(unsigned short, h);
}

DEVINL f16x8 ldfrag(const u16* p) {
    union { int2 d[2]; f16x8 v; } u;
    u.d[0] = *(const int2*)(p);
    u.d[1] = *(const int2*)(p + 4);
    return u.v;
}

// ---------------------------------------------------------------------------
// Shared GEMM core: C[i,j] = sum_k A[i,k]*B[j,k] (NT), fp16 in, f32 accum.
// 512 threads = 8 waves in 2x4; block tile 128x128; wave tile 64x32 (4x2).
// 2 waves/SIMD even at 1 block/CU -> latency hiding (round-1 fix: was 1/SIMD).
// ---------------------------------------------------------------------------
DEVINL void gemm_core(const u16* __restrict__ Ag, int lda,
                      const u16* __restrict__ Bg, int ldb,
                      int kOff, int kLen, u16* As, u16* Bs, f32x4 (&acc)[4][2])
{
    int tid = threadIdx.x;
    int r0 = tid >> 2;            // 0..127
    int kk0 = (tid & 3) * 8;      // 0,8,16,24
    int lane = tid & 63, w = tid >> 6;
    int wr = w >> 2, wc = w & 3;
    int kg = lane >> 4, rl = lane & 15;

    for (int k0 = 0; k0 < kLen; k0 += 32) {
        __syncthreads();
        int4 va = *(const int4*)(Ag + (size_t)r0 * lda + kOff + k0 + kk0);
        int4 vb = *(const int4*)(Bg + (size_t)r0 * ldb + kOff + k0 + kk0);
        u16* pa = &As[r0 * 40 + kk0];
        *(int2*)pa = make_int2(va.x, va.y);
        *(int2*)(pa + 4) = make_int2(va.z, va.w);
        u16* pb = &Bs[r0 * 40 + kk0];
        *(int2*)pb = make_int2(vb.x, vb.y);
        *(int2*)(pb + 4) = make_int2(vb.z, vb.w);
        __syncthreads();
        f16x8 af[4], bf[2];
#pragma unroll
        for (int i = 0; i < 4; ++i) af[i] = ldfrag(&As[(wr * 64 + i * 16 + rl) * 40 + kg * 8]);
#pragma unroll
        for (int j = 0; j < 2; ++j) bf[j] = ldfrag(&Bs[(wc * 32 + j * 16 + rl) * 40 + kg * 8]);
#pragma unroll
        for (int i = 0; i < 4; ++i)
#pragma unroll
            for (int j = 0; j < 2; ++j)
                acc[i][j] = __builtin_amdgcn_mfma_f32_16x16x32_f16(af[i], bf[j], acc[i][j], 0, 0, 0);
    }
}

// EPI: 0 = fp16 store + bias[col]; 1 = f32 store; 2 = split-K atomicAdd
//      (EPI 2: z -> {batch = z>>zshift, slice = z & mask})
template<int EPI>
__launch_bounds__(512)
__global__ void gemm512(const u16* __restrict__ A, int lda, long sAz,
                        const u16* __restrict__ B, int ldb, long sBz,
                        int K, int splitK, int zshift,
                        const float* __restrict__ bias,
                        void* outv, int ldo, long sOz)
{
    __shared__ u16 As[128 * 40];
    __shared__ u16 Bs[128 * 40];
    int z = blockIdx.z;
    int kOff = 0, kLen = K;
    long zo = 0;
    if (EPI == 2) {
        int bq = z >> zshift, s = z & ((1 << zshift) - 1);
        kOff = s * splitK; kLen = splitK;
        A += sAz * bq; B += sBz * bq; zo = sOz * bq;
    } else {
        A += sAz * z; B += sBz * z; zo = sOz * z;
    }
    int rowBase = blockIdx.y * 128, colBase = blockIdx.x * 128;
    f32x4 acc[4][2];
#pragma unroll
    for (int i = 0; i < 4; ++i)
#pragma unroll
        for (int j = 0; j < 2; ++j) acc[i][j] = (f32x4){0.f, 0.f, 0.f, 0.f};

    gemm_core(A + (size_t)rowBase * lda, lda, B + (size_t)colBase * ldb, ldb, kOff, kLen, As, Bs, acc);

    int lane = threadIdx.x & 63, w = threadIdx.x >> 6;
    int wr = w >> 2, wc = w & 3, kg = lane >> 4, rl = lane & 15;
    u16* outh = (u16*)outv;
    float* outf = (float*)outv;
#pragma unroll
    for (int i = 0; i < 4; ++i) {
        int row0 = rowBase + wr * 64 + i * 16 + kg * 4;
#pragma unroll
        for (int j = 0; j < 2; ++j) {
            int col = colBase + wc * 32 + j * 16 + rl;
            f32x4 v = acc[i][j];
#pragma unroll
            for (int r = 0; r < 4; ++r) {
                size_t o = (size_t)(row0 + r) * ldo + col;
                if (EPI == 0) outh[zo + o] = f2h_u(v[r] + bias[col]);
                else if (EPI == 1) outf[o] = v[r];
                else atomicAdd(&outf[zo + o], v[r]);
            }
        }
    }
}

// Fused apply GEMM: out = gamma * (A.B^T) + src, batched z = {bb,t} (bb=z>>1, t=z&1).
// APERZ: A indexed by z (PV: A=V2[b][t]), else by bb (channel: A=simc[b], B=Vt2[b][t]).
template<bool APERZ>
__launch_bounds__(512)
__global__ void gemm_fused(const u16* __restrict__ Ab, long sA, int lda,
                           const u16* __restrict__ Bb, long sB, int ldb, int K,
                           const float* __restrict__ g0p, const float* __restrict__ g1p,
                           const float* src0, const float* src1, long sS, int ldsrc,
                           float* out0, float* out1, long sO, int ldo)
{
    __shared__ u16 As[128 * 40];
    __shared__ u16 Bs[128 * 40];
    int z = blockIdx.z, bb = z >> 1, t = z & 1;
    const u16* A = Ab + (APERZ ? (long)z : (long)bb) * sA;
    const u16* B = Bb + (APERZ ? (long)bb : (long)z) * sB;
    const float* src = (t ? src1 : src0) + (long)bb * sS;
    float* out = (t ? out1 : out0) + (long)bb * sO;
    float gamma = t ? *g1p : *g0p;

    int rowBase = blockIdx.y * 128, colBase = blockIdx.x * 128;
    f32x4 acc[4][2];
#pragma unroll
    for (int i = 0; i < 4; ++i)
#pragma unroll
        for (int j = 0; j < 2; ++j) acc[i][j] = (f32x4){0.f, 0.f, 0.f, 0.f};

    gemm_core(A + (size_t)rowBase * lda, lda, B + (size_t)colBase * ldb, ldb, 0, K, As, Bs, acc);

    int lane = threadIdx.x & 63, w = threadIdx.x >> 6;
    int wr = w >> 2, wc = w & 3, kg = lane >> 4, rl = lane & 15;
#pragma unroll
    for (int i = 0; i < 4; ++i) {
        int row0 = rowBase + wr * 64 + i * 16 + kg * 4;
#pragma unroll
        for (int j = 0; j < 2; ++j) {
            int col = colBase + wc * 32 + j * 16 + rl;
            f32x4 v = acc[i][j];
#pragma unroll
            for (int r = 0; r < 4; ++r) {
                int row = row0 + r;
                out[(size_t)row * ldo + col] = gamma * v[r] + src[(size_t)row * ldsrc + col];
            }
        }
    }
}

// f32 [R][NC] -> fp16 [NC][R] transpose (64x64 LDS tiles)
__global__ void tr_f32_h(const float* __restrict__ in, u16* __restrict__ out,
                         int R, int NC_, long sIn, long sOut)
{
    in += (long)blockIdx.z * sIn; out += (long)blockIdx.z * sOut;
    __shared__ u16 s[64 * 65];
    int tx = threadIdx.x & 63, tw = threadIdx.x >> 6;
    int r0 = blockIdx.y * 64, c0 = blockIdx.x * 64;
#pragma unroll
    for (int p = 0; p < 16; ++p) {
        int r = tw + p * 4;
        s[tx * 65 + r] = f2h_u(in[(size_t)(r0 + r) * NC_ + c0 + tx]);
    }
    __syncthreads();
#pragma unroll
    for (int p = 0; p < 16; ++p) {
        int rr = tw + p * 4;
        out[(size_t)(c0 + rr) * R + r0 + tx] = s[rr * 65 + tx];
    }
}

// fp16 [R][NC] -> fp16 [NC][R]
__global__ void tr_h_h(const u16* __restrict__ in, u16* __restrict__ out,
                       int R, int NC_, long sIn, long sOut)
{
    in += (long)blockIdx.z * sIn; out += (long)blockIdx.z * sOut;
    __shared__ u16 s[64 * 65];
    int tx = threadIdx.x & 63, tw = threadIdx.x >> 6;
    int r0 = blockIdx.y * 64, c0 = blockIdx.x * 64;
#pragma unroll
    for (int p = 0; p < 16; ++p) {
        int r = tw + p * 4;
        s[tx * 65 + r] = in[(size_t)(r0 + r) * NC_ + c0 + tx];
    }
    __syncthreads();
#pragma unroll
    for (int p = 0; p < 16; ++p) {
        int rr = tw + p * 4;
        out[(size_t)(c0 + rr) * R + r0 + tx] = s[rr * 65 + tx];
    }
}

__global__ void cvt_w_kernel(const float* __restrict__ w0, const float* __restrict__ w1,
                             const float* __restrict__ w2, const float* __restrict__ w3,
                             u16* __restrict__ out)
{
    int i = blockIdx.x * 256 + threadIdx.x;
    const float* w = (i < 65536) ? w0 : (i < 131072) ? w1 : (i < 196608) ? w2 : w3;
    out[i] = f2h_u(w[i & 65535]);
}

// column-wise (over m) online max/sum-exp partials of St[4096][4096]
__global__ void colstats_partial(const float* __restrict__ St,
                                 float* __restrict__ pmax, float* __restrict__ psum)
{
    int col = blockIdx.x * 256 + threadIdx.x;
    int m0 = blockIdx.y * 256;
    float mx = -3.0e38f, sm = 0.f;
    for (int m = 0; m < 256; ++m) {
        float v = St[(size_t)(m0 + m) * 4096 + col];
        if (v > mx) { sm = sm * __expf(mx - v) + 1.f; mx = v; }
        else sm += __expf(v - mx);
    }
    pmax[blockIdx.y * 4096 + col] = mx;
    psum[blockIdx.y * 4096 + col] = sm;
}

__global__ void colstats_combine(const float* __restrict__ pmax, const float* __restrict__ psum,
                                 float* __restrict__ cmax, float* __restrict__ crcp)
{
    int col = blockIdx.x * 256 + threadIdx.x;
    float mx = -3.0e38f;
    for (int i = 0; i < 16; ++i) mx = fmaxf(mx, pmax[i * 4096 + col]);
    float s = 0.f;
    for (int i = 0; i < 16; ++i) s += psum[i * 4096 + col] * __expf(pmax[i * 4096 + col] - mx);
    cmax[col] = mx;
    crcp[col] = 1.f / s;
}

// Pt[m,n] = fp16( exp(St[m,n]-cmax[n]) * crcp[n] ), 4 cols/thread
__global__ void pt4_kernel(const float* __restrict__ St, const float* __restrict__ cmax,
                           const float* __restrict__ crcp, u16* __restrict__ Pt)
{
    int m = blockIdx.y;
    int c0 = (blockIdx.x * 256 + threadIdx.x) * 4;
    size_t o = (size_t)m * 4096 + c0;
    float4 s = *(const float4*)(St + o);
    float4 mx = *(const float4*)(cmax + c0);
    float4 rc = *(const float4*)(crcp + c0);
    u16 h0 = f2h_u(__expf(s.x - mx.x) * rc.x);
    u16 h1 = f2h_u(__expf(s.y - mx.y) * rc.y);
    u16 h2 = f2h_u(__expf(s.z - mx.z) * rc.z);
    u16 h3 = f2h_u(__expf(s.w - mx.w) * rc.w);
    uint2 pk;
    pk.x = (unsigned)h0 | ((unsigned)h1 << 16);
    pk.y = (unsigned)h2 | ((unsigned)h3 << 16);
    *(uint2*)(Pt + o) = pk;
}

DEVINL float blockReduce(float v, int op) {  // op 0 = max, 1 = sum; 256 threads
    __shared__ float s[4];
#pragma unroll
    for (int o = 32; o; o >>= 1) {
        float t = __shfl_xor(v, o, 64);
        v = op ? (v + t) : fmaxf(v, t);
    }
    __syncthreads();
    if ((threadIdx.x & 63) == 0) s[threadIdx.x >> 6] = v;
    __syncthreads();
    return op ? (s[0] + s[1] + s[2] + s[3]) : fmaxf(fmaxf(s[0], s[1]), fmaxf(s[2], s[3]));
}

// sim_c row softmax of (rowmax(E) - E) over d; E f32 [256][256]; y = local batch
__global__ void simc_kernel(const float* __restrict__ E, u16* __restrict__ simc)
{
    int bb = blockIdx.y;
    const float* Eb = E + bb * 65536;
    u16* sc = simc + bb * 65536;
    int c = blockIdx.x, d = threadIdx.x;
    float e = Eb[c * 256 + d];
    float rmax = blockReduce(e, 0);
    float v = rmax - e;
    float vmax = blockReduce(v, 0);
    float p = __expf(v - vmax);
    float s = blockReduce(p, 1);
    sc[c * 256 + d] = f2h_u(p / s);
}

extern "C" void kernel_launch(void* const* d_in, const int* in_sizes, int n_in,
                              void* d_out, int out_size, void* d_ws, size_t ws_size,
                              hipStream_t stream)
{
    const float* x      = (const float*)d_in[0];
    const float* xth    = (const float*)d_in[1];
    const float* Wk_rgb = (const float*)d_in[2];
    const float* bk_rgb = (const float*)d_in[3];
    const float* Wk_th  = (const float*)d_in[4];
    const float* bk_th  = (const float*)d_in[5];
    const float* Wv_rgb = (const float*)d_in[6];
    const float* bv_rgb = (const float*)d_in[7];
    const float* Wv_th  = (const float*)d_in[8];
    const float* bv_th  = (const float*)d_in[9];
    const float* g1r = (const float*)d_in[10];
    const float* g1t = (const float*)d_in[11];
    const float* g2r = (const float*)d_in[12];
    const float* g2t = (const float*)d_in[13];

    const long CN = 256L * 4096L;        // 1M elems per batch-tensor
    const long PtE = 4096L * 4096L;      // 16M elems

    // ws carve-up (~179 MB)
    u16* wts   = (u16*)d_ws;             // [4][256][256] fp16
    u16* Kt    = wts + 4 * 65536;        // [4][4096][256] x_k^T
    u16* Ktth  = Kt + 4 * CN;
    u16* Vt2   = Ktth + 4 * CN;          // [4][2][4096][256]  (t=0: x_v^T, t=1: x_v_th^T)
    u16* V2    = Vt2 + 8 * CN;           // [4][2][256][4096]
    u16* simc  = V2 + 8 * CN;            // [4][256][256]
    float* E   = (float*)(simc + 4 * 65536);  // [4][256][256] f32
    float* pmax = E + 4 * 65536;
    float* psum = pmax + 16 * 4096;
    float* cmax = psum + 16 * 4096;
    float* crcp = cmax + 4096;
    float* St   = crcp + 4096;           // [4096][4096] f32, reused per batch
    u16* Pt    = (u16*)(St + PtE);       // [2][4096][4096] fp16 (per batch-pair)
    u16* xT    = Pt;                     // alias: dead before first Pt write
    u16* xthT  = xT + 4 * CN;

    float* outX2  = (float*)d_out;
    float* outXt2 = outX2 + 4 * CN;

    cvt_w_kernel<<<1024, 256, 0, stream>>>(Wk_rgb, Wk_th, Wv_rgb, Wv_th, wts);
    tr_f32_h<<<dim3(64, 4, 4), 256, 0, stream>>>(x,   xT,   256, 4096, CN, CN);
    tr_f32_h<<<dim3(64, 4, 4), 256, 0, stream>>>(xth, xthT, 256, 4096, CN, CN);

    // projections -> [n][o] fp16; V projections interleave into Vt2 [b][t][n][c]
    gemm512<0><<<dim3(2, 32, 4), 512, 0, stream>>>(xT,   256, CN, wts,          256, 0, 256, 0, 0, bk_rgb, Kt,       256, CN);
    gemm512<0><<<dim3(2, 32, 4), 512, 0, stream>>>(xthT, 256, CN, wts + 65536,  256, 0, 256, 0, 0, bk_th,  Ktth,     256, CN);
    gemm512<0><<<dim3(2, 32, 4), 512, 0, stream>>>(xT,   256, CN, wts + 131072, 256, 0, 256, 0, 0, bv_rgb, Vt2,      256, 2 * CN);
    gemm512<0><<<dim3(2, 32, 4), 512, 0, stream>>>(xthT, 256, CN, wts + 196608, 256, 0, 256, 0, 0, bv_th,  Vt2 + CN, 256, 2 * CN);

    tr_h_h<<<dim3(4, 64, 8), 256, 0, stream>>>(Vt2, V2, 4096, 256, CN, CN);

    for (int p = 0; p < 2; ++p) {
        for (int lb = 0; lb < 2; ++lb) {
            int b = 2 * p + lb;
            gemm512<1><<<dim3(32, 32, 1), 512, 0, stream>>>(Kt + b * CN, 256, 0, Ktth + b * CN, 256, 0, 256, 0, 0, nullptr, St, 4096, 0);
            colstats_partial<<<dim3(16, 16), 256, 0, stream>>>(St, pmax, psum);
            colstats_combine<<<16, 256, 0, stream>>>(pmax, psum, cmax, crcp);
            pt4_kernel<<<dim3(4, 4096), 256, 0, stream>>>(St, cmax, crcp, Pt + (long)lb * PtE);
        }
        // x_1 = gamma1 * (V @ P) + x   (z = {lb,t}, 256 blocks)
        gemm_fused<true><<<dim3(32, 2, 4), 512, 0, stream>>>(
            V2 + (long)p * 4 * CN, CN, 4096, Pt, PtE, 4096, 4096,
            g1r, g1t, x + 2L * p * CN, xth + 2L * p * CN, CN, 4096,
            outX2 + 2L * p * CN, outXt2 + 2L * p * CN, CN, 4096);

        // energy[c,d] = sum_n Vth[c,n] V[d,n], batched split-K over the pair
        (void)hipMemsetAsync(E + 2L * p * 65536, 0, 2 * 65536 * sizeof(float), stream);
        gemm512<2><<<dim3(2, 2, 64), 512, 0, stream>>>(
            V2 + (long)p * 4 * CN + CN, 4096, 2 * CN,
            V2 + (long)p * 4 * CN,      4096, 2 * CN,
            4096, 128, 5, nullptr, E + 2L * p * 65536, 256, 65536);
        simc_kernel<<<dim3(256, 2), 256, 0, stream>>>(E + 2L * p * 65536, simc + 2L * p * 65536);

        // x_2 = gamma2 * (simc @ V) + x_1   (in-place on d_out)
        gemm_fused<false><<<dim3(32, 2, 4), 512, 0, stream>>>(
            simc + 2L * p * 65536, 65536, 256, Vt2 + (long)p * 4 * CN, CN, 256, 256,
            g2r, g2t, outX2 + 2L * p * CN, outXt2 + 2L * p * CN, CN, 4096,
            outX2 + 2L * p * CN, outXt2 + 2L * p * CN, CN, 4096);
    }
}

// Round 4
// 728.054 us; speedup vs baseline: 2.1846x; 1.0296x over previous
//
#include <hip/hip_runtime.h>

typedef unsigned short u16;
typedef __attribute__((ext_vector_type(8))) _Float16 f16x8;
typedef __attribute__((ext_vector_type(4))) float f32x4;

#define DEVINL __device__ __forceinline__

DEVINL u16 f2h_u(float f) { _Float16 h = (_Float16)f; return __builtin_bit_cast(unsigned short, h); }
DEVINL float h2f_u(u16 h) { return (float)__builtin_bit_cast(_Float16, h); }

DEVINL f16x8 ldfrag(const u16* p) {
    int4 d = *(const int4*)p;                 // ds_read_b128
    return __builtin_bit_cast(f16x8, d);
}

DEVINL void glds16(const u16* g, u16* l) {    // async global->LDS, 16B/lane
    __builtin_amdgcn_global_load_lds(
        (const __attribute__((address_space(1))) unsigned int*)g,
        (__attribute__((address_space(3))) unsigned int*)l, 16, 0, 0);
}

// ---------------------------------------------------------------------------
// NT GEMM core: C[i,j] = sum_k A[i,k]*B[j,k], fp16 in, f32 accum.
// 512 thr = 8 waves (2 row x 4 col); block tile 128x128, BK=32, wave 64x32.
// LDS linear [128][32] staged by global_load_lds; XOR swizzle confined to the
// 2 chunk bits (BK=32 -> 4 chunks of 8): source col ^= (row&3)<<3, and the
// frag ds_read applies the same XOR. (Round-3 bug: used (row&7)<<3, which
// walks out of the 32-col tile -> garbage -> NaN.)
// ---------------------------------------------------------------------------
DEVINL void gemm_core(const u16* __restrict__ Ag, int lda,
                      const u16* __restrict__ Bg, int ldb,
                      int kOff, int kLen, u16* As, u16* Bs, f32x4 (&acc)[4][2])
{
    int tid = threadIdx.x;
    int lane = tid & 63, w = tid >> 6;
    int wr = w >> 2, wc = w & 3;
    int kg = lane >> 4, rl = lane & 15;

    // staging: wave w owns rows w*16..+15; lane l -> row w*16+(l>>2), chunk l&3
    int srow = w * 16 + (lane >> 2);
    int scol = ((lane & 3) * 8) ^ ((srow & 3) << 3);       // pre-swizzled source col
    const u16* aSrc = Ag + (size_t)srow * lda + kOff + scol;
    const u16* bSrc = Bg + (size_t)srow * ldb + kOff + scol;
    u16* aDst = As + w * 512;                              // wave-uniform LDS base
    u16* bDst = Bs + w * 512;

    // frag-read offsets; row&3 == rl&3 since row base is a multiple of 16
    int swz = (kg * 8) ^ ((rl & 3) << 3);
    int aOff = (wr * 64 + rl) * 32 + swz;
    int bOff = (wc * 32 + rl) * 32 + swz;

    for (int k0 = 0; k0 < kLen; k0 += 32) {
        __syncthreads();                                   // LDS reusable
        glds16(aSrc + k0, aDst);
        glds16(bSrc + k0, bDst);
        __syncthreads();                                   // drains vmcnt
        f16x8 af[4], bf[2];
#pragma unroll
        for (int i = 0; i < 4; ++i) af[i] = ldfrag(&As[aOff + i * 512]);
#pragma unroll
        for (int j = 0; j < 2; ++j) bf[j] = ldfrag(&Bs[bOff + j * 512]);
#pragma unroll
        for (int i = 0; i < 4; ++i)
#pragma unroll
            for (int j = 0; j < 2; ++j)
                acc[i][j] = __builtin_amdgcn_mfma_f32_16x16x32_f16(af[i], bf[j], acc[i][j], 0, 0, 0);
    }
}

// EPI: 1 = fp16 store; 2 = split-K atomicAdd f32 (z -> {bq=z>>zshift, slice})
template<int EPI>
__launch_bounds__(512)
__global__ void gemm512(const u16* __restrict__ A, int lda, long sAz,
                        const u16* __restrict__ B, int ldb, long sBz,
                        int K, int splitK, int zshift,
                        void* outv, int ldo, long sOz)
{
    __shared__ __align__(16) u16 As[128 * 32];
    __shared__ __align__(16) u16 Bs[128 * 32];
    int z = blockIdx.z;
    int kOff = 0, kLen = K;
    long zo = 0;
    if (EPI == 2) {
        int bq = z >> zshift, s = z & ((1 << zshift) - 1);
        kOff = s * splitK; kLen = splitK;
        A += sAz * bq; B += sBz * bq; zo = sOz * bq;
    } else {
        A += sAz * z; B += sBz * z; zo = sOz * z;
    }
    int rowBase = blockIdx.y * 128, colBase = blockIdx.x * 128;
    f32x4 acc[4][2];
#pragma unroll
    for (int i = 0; i < 4; ++i)
#pragma unroll
        for (int j = 0; j < 2; ++j) acc[i][j] = (f32x4){0.f, 0.f, 0.f, 0.f};

    gemm_core(A + (size_t)rowBase * lda, lda, B + (size_t)colBase * ldb, ldb, kOff, kLen, As, Bs, acc);

    int lane = threadIdx.x & 63, w = threadIdx.x >> 6;
    int wr = w >> 2, wc = w & 3, kg = lane >> 4, rl = lane & 15;
    u16* outh = (u16*)outv;
    float* outf = (float*)outv;
#pragma unroll
    for (int i = 0; i < 4; ++i) {
        int row0 = rowBase + wr * 64 + i * 16 + kg * 4;
#pragma unroll
        for (int j = 0; j < 2; ++j) {
            int col = colBase + wc * 32 + j * 16 + rl;
            f32x4 v = acc[i][j];
#pragma unroll
            for (int r = 0; r < 4; ++r) {
                size_t o = (size_t)(row0 + r) * ldo + col;
                if (EPI == 1) outh[o] = f2h_u(v[r]);
                else atomicAdd(&outf[zo + o], v[r]);
            }
        }
    }
}

// all 16 projections in one dispatch: z = b*4 + t, out[n][o] fp16 + bias
__launch_bounds__(512)
__global__ void proj_all(const u16* __restrict__ xT, const u16* __restrict__ xthT,
                         const u16* __restrict__ wts,
                         const float* __restrict__ b0, const float* __restrict__ b1,
                         const float* __restrict__ b2, const float* __restrict__ b3,
                         u16* o0, u16* o1, u16* o2, u16* o3, long CN)
{
    __shared__ __align__(16) u16 As[128 * 32];
    __shared__ __align__(16) u16 Bs[128 * 32];
    int z = blockIdx.z, b = z >> 2, t = z & 3;
    const u16* A = ((t & 1) ? xthT : xT) + (long)b * CN;
    const u16* B = wts + t * 65536;
    const float* bias = t == 0 ? b0 : t == 1 ? b1 : t == 2 ? b2 : b3;
    u16* out = t == 0 ? o0 + (long)b * CN : t == 1 ? o1 + (long)b * CN
             : t == 2 ? o2 + (long)b * 2 * CN : o3 + (long)b * 2 * CN;
    int rowBase = blockIdx.y * 128, colBase = blockIdx.x * 128;
    f32x4 acc[4][2];
#pragma unroll
    for (int i = 0; i < 4; ++i)
#pragma unroll
        for (int j = 0; j < 2; ++j) acc[i][j] = (f32x4){0.f, 0.f, 0.f, 0.f};

    gemm_core(A + (size_t)rowBase * 256, 256, B + (size_t)colBase * 256, 256, 0, 256, As, Bs, acc);

    int lane = threadIdx.x & 63, w = threadIdx.x >> 6;
    int wr = w >> 2, wc = w & 3, kg = lane >> 4, rl = lane & 15;
#pragma unroll
    for (int i = 0; i < 4; ++i) {
        int row0 = rowBase + wr * 64 + i * 16 + kg * 4;
#pragma unroll
        for (int j = 0; j < 2; ++j) {
            int col = colBase + wc * 32 + j * 16 + rl;
            f32x4 v = acc[i][j];
#pragma unroll
            for (int r = 0; r < 4; ++r)
                out[(size_t)(row0 + r) * 256 + col] = f2h_u(v[r] + bias[col]);
        }
    }
}

// Fused apply GEMM: out = gamma*(A.B^T) + src, z = {bb = z>>1, t = z&1}.
// APERZ: A indexed by z (PV), else by bb (channel; B by z).
template<bool APERZ>
__launch_bounds__(512)
__global__ void gemm_fused(const u16* __restrict__ Ab, long sA, int lda,
                           const u16* __restrict__ Bb, long sB, int ldb, int K,
                           const float* __restrict__ g0p, const float* __restrict__ g1p,
                           const float* src0, const float* src1, long sS, int ldsrc,
                           float* out0, float* out1, long sO, int ldo)
{
    __shared__ __align__(16) u16 As[128 * 32];
    __shared__ __align__(16) u16 Bs[128 * 32];
    int z = blockIdx.z, bb = z >> 1, t = z & 1;
    const u16* A = Ab + (APERZ ? (long)z : (long)bb) * sA;
    const u16* B = Bb + (APERZ ? (long)bb : (long)z) * sB;
    const float* src = (t ? src1 : src0) + (long)bb * sS;
    float* out = (t ? out1 : out0) + (long)bb * sO;
    float gamma = t ? *g1p : *g0p;

    int rowBase = blockIdx.y * 128, colBase = blockIdx.x * 128;
    f32x4 acc[4][2];
#pragma unroll
    for (int i = 0; i < 4; ++i)
#pragma unroll
        for (int j = 0; j < 2; ++j) acc[i][j] = (f32x4){0.f, 0.f, 0.f, 0.f};

    gemm_core(A + (size_t)rowBase * lda, lda, B + (size_t)colBase * ldb, ldb, 0, K, As, Bs, acc);

    int lane = threadIdx.x & 63, w = threadIdx.x >> 6;
    int wr = w >> 2, wc = w & 3, kg = lane >> 4, rl = lane & 15;
#pragma unroll
    for (int i = 0; i < 4; ++i) {
        int row0 = rowBase + wr * 64 + i * 16 + kg * 4;
#pragma unroll
        for (int j = 0; j < 2; ++j) {
            int col = colBase + wc * 32 + j * 16 + rl;
            f32x4 v = acc[i][j];
#pragma unroll
            for (int r = 0; r < 4; ++r) {
                int row = row0 + r;
                out[(size_t)row * ldo + col] = gamma * v[r] + src[(size_t)row * ldsrc + col];
            }
        }
    }
}

// f32 [R][NC] -> fp16 [NC][R] transpose (64x64 LDS tiles)
__global__ void tr_f32_h(const float* __restrict__ in, u16* __restrict__ out,
                         int R, int NC_, long sIn, long sOut)
{
    in += (long)blockIdx.z * sIn; out += (long)blockIdx.z * sOut;
    __shared__ u16 s[64 * 65];
    int tx = threadIdx.x & 63, tw = threadIdx.x >> 6;
    int r0 = blockIdx.y * 64, c0 = blockIdx.x * 64;
#pragma unroll
    for (int p = 0; p < 16; ++p) {
        int r = tw + p * 4;
        s[tx * 65 + r] = f2h_u(in[(size_t)(r0 + r) * NC_ + c0 + tx]);
    }
    __syncthreads();
#pragma unroll
    for (int p = 0; p < 16; ++p) {
        int rr = tw + p * 4;
        out[(size_t)(c0 + rr) * R + r0 + tx] = s[rr * 65 + tx];
    }
}

// fp16 [R][NC] -> fp16 [NC][R]
__global__ void tr_h_h(const u16* __restrict__ in, u16* __restrict__ out,
                       int R, int NC_, long sIn, long sOut)
{
    in += (long)blockIdx.z * sIn; out += (long)blockIdx.z * sOut;
    __shared__ u16 s[64 * 65];
    int tx = threadIdx.x & 63, tw = threadIdx.x >> 6;
    int r0 = blockIdx.y * 64, c0 = blockIdx.x * 64;
#pragma unroll
    for (int p = 0; p < 16; ++p) {
        int r = tw + p * 4;
        s[tx * 65 + r] = in[(size_t)(r0 + r) * NC_ + c0 + tx];
    }
    __syncthreads();
#pragma unroll
    for (int p = 0; p < 16; ++p) {
        int rr = tw + p * 4;
        out[(size_t)(c0 + rr) * R + r0 + tx] = s[rr * 65 + tx];
    }
}

__global__ void cvt_w_kernel(const float* __restrict__ w0, const float* __restrict__ w1,
                             const float* __restrict__ w2, const float* __restrict__ w3,
                             u16* __restrict__ out)
{
    int i = blockIdx.x * 256 + threadIdx.x;
    const float* w = (i < 65536) ? w0 : (i < 131072) ? w1 : (i < 196608) ? w2 : w3;
    out[i] = f2h_u(w[i & 65535]);
}

// column-wise (over m) online max/sum-exp partials of fp16 St[4096][4096]
__global__ void colstats_partial(const u16* __restrict__ St,
                                 float* __restrict__ pmax, float* __restrict__ psum)
{
    int col = blockIdx.x * 256 + threadIdx.x;
    int m0 = blockIdx.y * 256;
    float mx = -3.0e38f, sm = 0.f;
    for (int m = 0; m < 256; ++m) {
        float v = h2f_u(St[(size_t)(m0 + m) * 4096 + col]);
        if (v > mx) { sm = sm * __expf(mx - v) + 1.f; mx = v; }
        else sm += __expf(v - mx);
    }
    pmax[blockIdx.y * 4096 + col] = mx;
    psum[blockIdx.y * 4096 + col] = sm;
}

__global__ void colstats_combine(const float* __restrict__ pmax, const float* __restrict__ psum,
                                 float* __restrict__ cmax, float* __restrict__ crcp)
{
    int col = blockIdx.x * 256 + threadIdx.x;
    float mx = -3.0e38f;
    for (int i = 0; i < 16; ++i) mx = fmaxf(mx, pmax[i * 4096 + col]);
    float s = 0.f;
    for (int i = 0; i < 16; ++i) s += psum[i * 4096 + col] * __expf(pmax[i * 4096 + col] - mx);
    cmax[col] = mx;
    crcp[col] = 1.f / s;
}

// in-place Pt[m,n] = fp16( exp(St[m,n]-cmax[n]) * crcp[n] ), 8 cols/thread
__global__ void pt8_kernel(u16* St, const float* __restrict__ cmax,
                           const float* __restrict__ crcp)
{
    int m = blockIdx.y;
    int c0 = threadIdx.x * 8;
    size_t o = (size_t)m * 4096 + c0;
    f16x8 hv = __builtin_bit_cast(f16x8, *(const int4*)(St + o));
    union { u16 q[8]; int4 v; } pk;
#pragma unroll
    for (int j = 0; j < 8; ++j)
        pk.q[j] = f2h_u(__expf((float)hv[j] - cmax[c0 + j]) * crcp[c0 + j]);
    *(int4*)(St + o) = pk.v;
}

DEVINL float blockReduce(float v, int op) {  // op 0 = max, 1 = sum; 256 threads
    __shared__ float s[4];
#pragma unroll
    for (int o = 32; o; o >>= 1) {
        float t = __shfl_xor(v, o, 64);
        v = op ? (v + t) : fmaxf(v, t);
    }
    __syncthreads();
    if ((threadIdx.x & 63) == 0) s[threadIdx.x >> 6] = v;
    __syncthreads();
    return op ? (s[0] + s[1] + s[2] + s[3]) : fmaxf(fmaxf(s[0], s[1]), fmaxf(s[2], s[3]));
}

// sim_c row softmax of (rowmax(E) - E) over d; E f32 [256][256]; y = local batch
__global__ void simc_kernel(const float* __restrict__ E, u16* __restrict__ simc)
{
    int bb = blockIdx.y;
    const float* Eb = E + bb * 65536;
    u16* sc = simc + bb * 65536;
    int c = blockIdx.x, d = threadIdx.x;
    float e = Eb[c * 256 + d];
    float rmax = blockReduce(e, 0);
    float v = rmax - e;
    float vmax = blockReduce(v, 0);
    float p = __expf(v - vmax);
    float s = blockReduce(p, 1);
    sc[c * 256 + d] = f2h_u(p / s);
}

extern "C" void kernel_launch(void* const* d_in, const int* in_sizes, int n_in,
                              void* d_out, int out_size, void* d_ws, size_t ws_size,
                              hipStream_t stream)
{
    const float* x      = (const float*)d_in[0];
    const float* xth    = (const float*)d_in[1];
    const float* Wk_rgb = (const float*)d_in[2];
    const float* bk_rgb = (const float*)d_in[3];
    const float* Wk_th  = (const float*)d_in[4];
    const float* bk_th  = (const float*)d_in[5];
    const float* Wv_rgb = (const float*)d_in[6];
    const float* bv_rgb = (const float*)d_in[7];
    const float* Wv_th  = (const float*)d_in[8];
    const float* bv_th  = (const float*)d_in[9];
    const float* g1r = (const float*)d_in[10];
    const float* g1t = (const float*)d_in[11];
    const float* g2r = (const float*)d_in[12];
    const float* g2t = (const float*)d_in[13];

    const long CN = 256L * 4096L;        // 1M elems per batch-tensor
    const long PtE = 4096L * 4096L;      // 16M elems

    // ws carve-up (~116 MB)
    u16* wts   = (u16*)d_ws;             // [4][256][256] fp16
    u16* Kt    = wts + 4 * 65536;        // [4][4096][256] x_k^T
    u16* Ktth  = Kt + 4 * CN;
    u16* Vt2   = Ktth + 4 * CN;          // [4][2][4096][256] (t=0: x_v^T, 1: x_v_th^T)
    u16* V2    = Vt2 + 8 * CN;           // [4][2][256][4096]
    u16* simc  = V2 + 8 * CN;            // [4][256][256]
    u16* StH   = simc + 4 * 65536;       // [2][4096][4096] fp16 St -> Pt in place
    float* E    = (float*)(StH + 2 * PtE);  // [4][256][256] f32
    float* pmax = E + 4 * 65536;
    float* psum = pmax + 16 * 4096;
    float* cmax = psum + 16 * 4096;
    float* crcp = cmax + 4096;
    u16* xT    = StH;                    // alias: dead before first StH write
    u16* xthT  = xT + 4 * CN;

    float* outX2  = (float*)d_out;
    float* outXt2 = outX2 + 4 * CN;

    cvt_w_kernel<<<1024, 256, 0, stream>>>(Wk_rgb, Wk_th, Wv_rgb, Wv_th, wts);
    tr_f32_h<<<dim3(64, 4, 4), 256, 0, stream>>>(x,   xT,   256, 4096, CN, CN);
    tr_f32_h<<<dim3(64, 4, 4), 256, 0, stream>>>(xth, xthT, 256, 4096, CN, CN);

    // all 16 projections, one dispatch (1024 blocks)
    proj_all<<<dim3(2, 32, 16), 512, 0, stream>>>(xT, xthT, wts,
        bk_rgb, bk_th, bv_rgb, bv_th, Kt, Ktth, Vt2, Vt2 + CN, CN);

    tr_h_h<<<dim3(4, 64, 8), 256, 0, stream>>>(Vt2, V2, 4096, 256, CN, CN);

    for (int p = 0; p < 2; ++p) {
        for (int lb = 0; lb < 2; ++lb) {
            int b = 2 * p + lb;
            u16* St = StH + (long)lb * PtE;
            gemm512<1><<<dim3(32, 32, 1), 512, 0, stream>>>(
                Kt + b * CN, 256, 0, Ktth + b * CN, 256, 0, 256, 0, 0, St, 4096, 0);
            colstats_partial<<<dim3(16, 16), 256, 0, stream>>>(St, pmax, psum);
            colstats_combine<<<16, 256, 0, stream>>>(pmax, psum, cmax, crcp);
            pt8_kernel<<<dim3(1, 4096), 512, 0, stream>>>(St, cmax, crcp);
        }
        // x_1 = gamma1 * (V @ P) + x   (z = {lb,t}, 256 blocks)
        gemm_fused<true><<<dim3(32, 2, 4), 512, 0, stream>>>(
            V2 + (long)p * 4 * CN, CN, 4096, StH, PtE, 4096, 4096,
            g1r, g1t, x + 2L * p * CN, xth + 2L * p * CN, CN, 4096,
            outX2 + 2L * p * CN, outXt2 + 2L * p * CN, CN, 4096);

        // energy[c,d] = sum_n Vth[c,n] V[d,n], batched split-K (64 slices of 64)
        (void)hipMemsetAsync(E + 2L * p * 65536, 0, 2 * 65536 * sizeof(float), stream);
        gemm512<2><<<dim3(2, 2, 128), 512, 0, stream>>>(
            V2 + (long)p * 4 * CN + CN, 4096, 2 * CN,
            V2 + (long)p * 4 * CN,      4096, 2 * CN,
            4096, 64, 6, E + 2L * p * 65536, 256, 65536);
        simc_kernel<<<dim3(256, 2), 256, 0, stream>>>(E + 2L * p * 65536, simc + 2L * p * 65536);

        // x_2 = gamma2 * (simc @ V) + x_1   (in-place on d_out)
        gemm_fused<false><<<dim3(32, 2, 4), 512, 0, stream>>>(
            simc + 2L * p * 65536, 65536, 256, Vt2 + (long)p * 4 * CN, CN, 256, 256,
            g2r, g2t, outX2 + 2L * p * CN, outXt2 + 2L * p * CN, CN, 4096,
            outX2 + 2L * p * CN, outXt2 + 2L * p * CN, CN, 4096);
    }
}

// Round 5
// 723.376 us; speedup vs baseline: 2.1988x; 1.0065x over previous
//
#include <hip/hip_runtime.h>

typedef unsigned short u16;
typedef __attribute__((ext_vector_type(8))) _Float16 f16x8;
typedef __attribute__((ext_vector_type(4))) float f32x4;

#define DEVINL __device__ __forceinline__

DEVINL u16 f2h_u(float f) { _Float16 h = (_Float16)f; return __builtin_bit_cast(unsigned short, h); }
DEVINL float h2f_u(u16 h) { return (float)__builtin_bit_cast(_Float16, h); }

DEVINL f16x8 ldfrag(const u16* p) {
    int4 d = *(const int4*)p;                 // ds_read_b128
    return __builtin_bit_cast(f16x8, d);
}

DEVINL void glds16(const u16* g, u16* l) {    // async global->LDS, 16B/lane
    __builtin_amdgcn_global_load_lds(
        (const __attribute__((address_space(1))) unsigned int*)g,
        (__attribute__((address_space(3))) unsigned int*)l, 16, 0, 0);
}

#define CFENCE asm volatile("" ::: "memory")           // compiler-only fence
#define VMCNT2 asm volatile("s_waitcnt vmcnt(2)" ::: "memory")
#define VMCNT0 asm volatile("s_waitcnt vmcnt(0)" ::: "memory")

// ---------------------------------------------------------------------------
// NT GEMM core: C[i,j] = sum_k A[i,k]*B[j,k], fp16 in, f32 accum.
// 512 thr = 8 waves (2 row x 4 col); block tile 128x128, BK=32, wave 64x32.
// 3-deep LDS pipeline, counted vmcnt (T3+T4 minimum):
//   iter t: vmcnt(2) [tile t landed; t+1 in flight] -> s_barrier -> CFENCE
//           -> stage(t+2) -> ds_read(t) -> MFMA(t)
// WAR on buf[(t+2)%3]: last read iter t-1, separated by this iter's barrier.
// RAW on buf[t]: own wave via vmcnt(2) (2 glds/tile), others via barrier.
// CFENCE pins ds_reads after the raw barrier (s_barrier is no compiler fence).
// Chunk-XOR swizzle (2 bits, BK=32): src col ^= (row&3)<<3, same on ds_read.
// ---------------------------------------------------------------------------
DEVINL void gemm_core(const u16* __restrict__ Ag, int lda,
                      const u16* __restrict__ Bg, int ldb,
                      int kOff, int kLen, u16* As, u16* Bs, f32x4 (&acc)[4][2])
{
    int tid = threadIdx.x;
    int lane = tid & 63, w = tid >> 6;
    int wr = w >> 2, wc = w & 3;
    int kg = lane >> 4, rl = lane & 15;

    // staging: wave w owns rows w*16..+15; lane l -> row w*16+(l>>2), chunk l&3
    int srow = w * 16 + (lane >> 2);
    int scol = ((lane & 3) * 8) ^ ((srow & 3) << 3);       // pre-swizzled source col
    const u16* aSrc = Ag + (size_t)srow * lda + kOff + scol;
    const u16* bSrc = Bg + (size_t)srow * ldb + kOff + scol;
    int dstOff = w * 512;                                  // wave-uniform LDS base

    // frag-read offsets; row&3 == rl&3 since row base is a multiple of 16
    int swz = (kg * 8) ^ ((rl & 3) << 3);
    int aOff = (wr * 64 + rl) * 32 + swz;
    int bOff = (wc * 32 + rl) * 32 + swz;

    int nt = kLen >> 5;
    // prologue: tiles 0,1 -> bufs 0,1
    glds16(aSrc,      As + dstOff);
    glds16(bSrc,      Bs + dstOff);
    glds16(aSrc + 32, As + 4096 + dstOff);
    glds16(bSrc + 32, Bs + 4096 + dstOff);

    int cur = 0;
    for (int t = 0; t < nt; ++t) {
        if (t + 1 < nt) { VMCNT2; } else { VMCNT0; }
        __builtin_amdgcn_s_barrier();
        CFENCE;
        if (t + 2 < nt) {
            int nb = cur + 2; if (nb >= 3) nb -= 3;
            glds16(aSrc + (size_t)(t + 2) * 32, As + nb * 4096 + dstOff);
            glds16(bSrc + (size_t)(t + 2) * 32, Bs + nb * 4096 + dstOff);
        }
        const u16* Ab = As + cur * 4096;
        const u16* Bb = Bs + cur * 4096;
        f16x8 af[4], bf[2];
#pragma unroll
        for (int i = 0; i < 4; ++i) af[i] = ldfrag(&Ab[aOff + i * 512]);
#pragma unroll
        for (int j = 0; j < 2; ++j) bf[j] = ldfrag(&Bb[bOff + j * 512]);
#pragma unroll
        for (int i = 0; i < 4; ++i)
#pragma unroll
            for (int j = 0; j < 2; ++j)
                acc[i][j] = __builtin_amdgcn_mfma_f32_16x16x32_f16(af[i], bf[j], acc[i][j], 0, 0, 0);
        cur = cur + 1; if (cur == 3) cur = 0;
    }
}

// EPI: 1 = fp16 store; 2 = split-K atomicAdd f32 (z -> {bq=z>>zshift, slice})
template<int EPI>
__launch_bounds__(512)
__global__ void gemm512(const u16* __restrict__ A, int lda, long sAz,
                        const u16* __restrict__ B, int ldb, long sBz,
                        int K, int splitK, int zshift,
                        void* outv, int ldo, long sOz)
{
    __shared__ __align__(16) u16 As[3 * 4096];
    __shared__ __align__(16) u16 Bs[3 * 4096];
    int z = blockIdx.z;
    int kOff = 0, kLen = K;
    long zo = 0;
    if (EPI == 2) {
        int bq = z >> zshift, s = z & ((1 << zshift) - 1);
        kOff = s * splitK; kLen = splitK;
        A += sAz * bq; B += sBz * bq; zo = sOz * bq;
    } else {
        A += sAz * z; B += sBz * z; zo = sOz * z;
    }
    int rowBase = blockIdx.y * 128, colBase = blockIdx.x * 128;
    f32x4 acc[4][2];
#pragma unroll
    for (int i = 0; i < 4; ++i)
#pragma unroll
        for (int j = 0; j < 2; ++j) acc[i][j] = (f32x4){0.f, 0.f, 0.f, 0.f};

    gemm_core(A + (size_t)rowBase * lda, lda, B + (size_t)colBase * ldb, ldb, kOff, kLen, As, Bs, acc);

    int lane = threadIdx.x & 63, w = threadIdx.x >> 6;
    int wr = w >> 2, wc = w & 3, kg = lane >> 4, rl = lane & 15;
    u16* outh = (u16*)outv;
    float* outf = (float*)outv;
#pragma unroll
    for (int i = 0; i < 4; ++i) {
        int row0 = rowBase + wr * 64 + i * 16 + kg * 4;
#pragma unroll
        for (int j = 0; j < 2; ++j) {
            int col = colBase + wc * 32 + j * 16 + rl;
            f32x4 v = acc[i][j];
#pragma unroll
            for (int r = 0; r < 4; ++r) {
                size_t o = (size_t)(row0 + r) * ldo + col;
                if (EPI == 1) outh[o] = f2h_u(v[r]);
                else atomicAdd(&outf[zo + o], v[r]);
            }
        }
    }
}

// all 16 projections in one dispatch: z = b*4 + t, out[n][o] fp16 + bias
__launch_bounds__(512)
__global__ void proj_all(const u16* __restrict__ xT, const u16* __restrict__ xthT,
                         const u16* __restrict__ wts,
                         const float* __restrict__ b0, const float* __restrict__ b1,
                         const float* __restrict__ b2, const float* __restrict__ b3,
                         u16* o0, u16* o1, u16* o2, u16* o3, long CN)
{
    __shared__ __align__(16) u16 As[3 * 4096];
    __shared__ __align__(16) u16 Bs[3 * 4096];
    int z = blockIdx.z, b = z >> 2, t = z & 3;
    const u16* A = ((t & 1) ? xthT : xT) + (long)b * CN;
    const u16* B = wts + t * 65536;
    const float* bias = t == 0 ? b0 : t == 1 ? b1 : t == 2 ? b2 : b3;
    u16* out = t == 0 ? o0 + (long)b * CN : t == 1 ? o1 + (long)b * CN
             : t == 2 ? o2 + (long)b * 2 * CN : o3 + (long)b * 2 * CN;
    int rowBase = blockIdx.y * 128, colBase = blockIdx.x * 128;
    f32x4 acc[4][2];
#pragma unroll
    for (int i = 0; i < 4; ++i)
#pragma unroll
        for (int j = 0; j < 2; ++j) acc[i][j] = (f32x4){0.f, 0.f, 0.f, 0.f};

    gemm_core(A + (size_t)rowBase * 256, 256, B + (size_t)colBase * 256, 256, 0, 256, As, Bs, acc);

    int lane = threadIdx.x & 63, w = threadIdx.x >> 6;
    int wr = w >> 2, wc = w & 3, kg = lane >> 4, rl = lane & 15;
#pragma unroll
    for (int i = 0; i < 4; ++i) {
        int row0 = rowBase + wr * 64 + i * 16 + kg * 4;
#pragma unroll
        for (int j = 0; j < 2; ++j) {
            int col = colBase + wc * 32 + j * 16 + rl;
            f32x4 v = acc[i][j];
#pragma unroll
            for (int r = 0; r < 4; ++r)
                out[(size_t)(row0 + r) * 256 + col] = f2h_u(v[r] + bias[col]);
        }
    }
}

// Fused apply GEMM: out = gamma*(A.B^T) + src, z = {bb = z>>1, t = z&1}.
// APERZ: A indexed by z (PV), else by bb (channel; B by z).
template<bool APERZ>
__launch_bounds__(512)
__global__ void gemm_fused(const u16* __restrict__ Ab, long sA, int lda,
                           const u16* __restrict__ Bb, long sB, int ldb, int K,
                           const float* __restrict__ g0p, const float* __restrict__ g1p,
                           const float* src0, const float* src1, long sS, int ldsrc,
                           float* out0, float* out1, long sO, int ldo)
{
    __shared__ __align__(16) u16 As[3 * 4096];
    __shared__ __align__(16) u16 Bs[3 * 4096];
    int z = blockIdx.z, bb = z >> 1, t = z & 1;
    const u16* A = Ab + (APERZ ? (long)z : (long)bb) * sA;
    const u16* B = Bb + (APERZ ? (long)bb : (long)z) * sB;
    const float* src = (t ? src1 : src0) + (long)bb * sS;
    float* out = (t ? out1 : out0) + (long)bb * sO;
    float gamma = t ? *g1p : *g0p;

    int rowBase = blockIdx.y * 128, colBase = blockIdx.x * 128;
    f32x4 acc[4][2];
#pragma unroll
    for (int i = 0; i < 4; ++i)
#pragma unroll
        for (int j = 0; j < 2; ++j) acc[i][j] = (f32x4){0.f, 0.f, 0.f, 0.f};

    gemm_core(A + (size_t)rowBase * lda, lda, B + (size_t)colBase * ldb, ldb, 0, K, As, Bs, acc);

    int lane = threadIdx.x & 63, w = threadIdx.x >> 6;
    int wr = w >> 2, wc = w & 3, kg = lane >> 4, rl = lane & 15;
#pragma unroll
    for (int i = 0; i < 4; ++i) {
        int row0 = rowBase + wr * 64 + i * 16 + kg * 4;
#pragma unroll
        for (int j = 0; j < 2; ++j) {
            int col = colBase + wc * 32 + j * 16 + rl;
            f32x4 v = acc[i][j];
#pragma unroll
            for (int r = 0; r < 4; ++r) {
                int row = row0 + r;
                out[(size_t)row * ldo + col] = gamma * v[r] + src[(size_t)row * ldsrc + col];
            }
        }
    }
}

// f32 [R][NC] -> fp16 [NC][R] transpose (64x64 LDS tiles)
__global__ void tr_f32_h(const float* __restrict__ in, u16* __restrict__ out,
                         int R, int NC_, long sIn, long sOut)
{
    in += (long)blockIdx.z * sIn; out += (long)blockIdx.z * sOut;
    __shared__ u16 s[64 * 65];
    int tx = threadIdx.x & 63, tw = threadIdx.x >> 6;
    int r0 = blockIdx.y * 64, c0 = blockIdx.x * 64;
#pragma unroll
    for (int p = 0; p < 16; ++p) {
        int r = tw + p * 4;
        s[tx * 65 + r] = f2h_u(in[(size_t)(r0 + r) * NC_ + c0 + tx]);
    }
    __syncthreads();
#pragma unroll
    for (int p = 0; p < 16; ++p) {
        int rr = tw + p * 4;
        out[(size_t)(c0 + rr) * R + r0 + tx] = s[rr * 65 + tx];
    }
}

// fp16 [R][NC] -> fp16 [NC][R]
__global__ void tr_h_h(const u16* __restrict__ in, u16* __restrict__ out,
                       int R, int NC_, long sIn, long sOut)
{
    in += (long)blockIdx.z * sIn; out += (long)blockIdx.z * sOut;
    __shared__ u16 s[64 * 65];
    int tx = threadIdx.x & 63, tw = threadIdx.x >> 6;
    int r0 = blockIdx.y * 64, c0 = blockIdx.x * 64;
#pragma unroll
    for (int p = 0; p < 16; ++p) {
        int r = tw + p * 4;
        s[tx * 65 + r] = in[(size_t)(r0 + r) * NC_ + c0 + tx];
    }
    __syncthreads();
#pragma unroll
    for (int p = 0; p < 16; ++p) {
        int rr = tw + p * 4;
        out[(size_t)(c0 + rr) * R + r0 + tx] = s[rr * 65 + tx];
    }
}

__global__ void cvt_w_kernel(const float* __restrict__ w0, const float* __restrict__ w1,
                             const float* __restrict__ w2, const float* __restrict__ w3,
                             u16* __restrict__ out)
{
    int i = blockIdx.x * 256 + threadIdx.x;
    const float* w = (i < 65536) ? w0 : (i < 131072) ? w1 : (i < 196608) ? w2 : w3;
    out[i] = f2h_u(w[i & 65535]);
}

// column-wise (over m) online max/sum-exp partials of fp16 St[4096][4096]
__global__ void colstats_partial(const u16* __restrict__ St,
                                 float* __restrict__ pmax, float* __restrict__ psum)
{
    int col = blockIdx.x * 256 + threadIdx.x;
    int m0 = blockIdx.y * 256;
    float mx = -3.0e38f, sm = 0.f;
    for (int m = 0; m < 256; ++m) {
        float v = h2f_u(St[(size_t)(m0 + m) * 4096 + col]);
        if (v > mx) { sm = sm * __expf(mx - v) + 1.f; mx = v; }
        else sm += __expf(v - mx);
    }
    pmax[blockIdx.y * 4096 + col] = mx;
    psum[blockIdx.y * 4096 + col] = sm;
}

__global__ void colstats_combine(const float* __restrict__ pmax, const float* __restrict__ psum,
                                 float* __restrict__ cmax, float* __restrict__ crcp)
{
    int col = blockIdx.x * 256 + threadIdx.x;
    float mx = -3.0e38f;
    for (int i = 0; i < 16; ++i) mx = fmaxf(mx, pmax[i * 4096 + col]);
    float s = 0.f;
    for (int i = 0; i < 16; ++i) s += psum[i * 4096 + col] * __expf(pmax[i * 4096 + col] - mx);
    cmax[col] = mx;
    crcp[col] = 1.f / s;
}

// in-place Pt[m,n] = fp16( exp(St[m,n]-cmax[n]) * crcp[n] ), 8 cols/thread
__global__ void pt8_kernel(u16* St, const float* __restrict__ cmax,
                           const float* __restrict__ crcp)
{
    int m = blockIdx.y;
    int c0 = threadIdx.x * 8;
    size_t o = (size_t)m * 4096 + c0;
    f16x8 hv = __builtin_bit_cast(f16x8, *(const int4*)(St + o));
    union { u16 q[8]; int4 v; } pk;
#pragma unroll
    for (int j = 0; j < 8; ++j)
        pk.q[j] = f2h_u(__expf((float)hv[j] - cmax[c0 + j]) * crcp[c0 + j]);
    *(int4*)(St + o) = pk.v;
}

DEVINL float blockReduce(float v, int op) {  // op 0 = max, 1 = sum; 256 threads
    __shared__ float s[4];
#pragma unroll
    for (int o = 32; o; o >>= 1) {
        float t = __shfl_xor(v, o, 64);
        v = op ? (v + t) : fmaxf(v, t);
    }
    __syncthreads();
    if ((threadIdx.x & 63) == 0) s[threadIdx.x >> 6] = v;
    __syncthreads();
    return op ? (s[0] + s[1] + s[2] + s[3]) : fmaxf(fmaxf(s[0], s[1]), fmaxf(s[2], s[3]));
}

// sim_c row softmax of (rowmax(E) - E) over d; E f32 [256][256]; y = local batch
__global__ void simc_kernel(const float* __restrict__ E, u16* __restrict__ simc)
{
    int bb = blockIdx.y;
    const float* Eb = E + bb * 65536;
    u16* sc = simc + bb * 65536;
    int c = blockIdx.x, d = threadIdx.x;
    float e = Eb[c * 256 + d];
    float rmax = blockReduce(e, 0);
    float v = rmax - e;
    float vmax = blockReduce(v, 0);
    float p = __expf(v - vmax);
    float s = blockReduce(p, 1);
    sc[c * 256 + d] = f2h_u(p / s);
}

extern "C" void kernel_launch(void* const* d_in, const int* in_sizes, int n_in,
                              void* d_out, int out_size, void* d_ws, size_t ws_size,
                              hipStream_t stream)
{
    const float* x      = (const float*)d_in[0];
    const float* xth    = (const float*)d_in[1];
    const float* Wk_rgb = (const float*)d_in[2];
    const float* bk_rgb = (const float*)d_in[3];
    const float* Wk_th  = (const float*)d_in[4];
    const float* bk_th  = (const float*)d_in[5];
    const float* Wv_rgb = (const float*)d_in[6];
    const float* bv_rgb = (const float*)d_in[7];
    const float* Wv_th  = (const float*)d_in[8];
    const float* bv_th  = (const float*)d_in[9];
    const float* g1r = (const float*)d_in[10];
    const float* g1t = (const float*)d_in[11];
    const float* g2r = (const float*)d_in[12];
    const float* g2t = (const float*)d_in[13];

    const long CN = 256L * 4096L;        // 1M elems per batch-tensor
    const long PtE = 4096L * 4096L;      // 16M elems

    // ws carve-up (~116 MB)
    u16* wts   = (u16*)d_ws;             // [4][256][256] fp16
    u16* Kt    = wts + 4 * 65536;        // [4][4096][256] x_k^T
    u16* Ktth  = Kt + 4 * CN;
    u16* Vt2   = Ktth + 4 * CN;          // [4][2][4096][256] (t=0: x_v^T, 1: x_v_th^T)
    u16* V2    = Vt2 + 8 * CN;           // [4][2][256][4096]
    u16* simc  = V2 + 8 * CN;            // [4][256][256]
    u16* StH   = simc + 4 * 65536;       // [2][4096][4096] fp16 St -> Pt in place
    float* E    = (float*)(StH + 2 * PtE);  // [4][256][256] f32
    float* pmax = E + 4 * 65536;
    float* psum = pmax + 16 * 4096;
    float* cmax = psum + 16 * 4096;
    float* crcp = cmax + 4096;
    u16* xT    = StH;                    // alias: dead before first StH write
    u16* xthT  = xT + 4 * CN;

    float* outX2  = (float*)d_out;
    float* outXt2 = outX2 + 4 * CN;

    cvt_w_kernel<<<1024, 256, 0, stream>>>(Wk_rgb, Wk_th, Wv_rgb, Wv_th, wts);
    tr_f32_h<<<dim3(64, 4, 4), 256, 0, stream>>>(x,   xT,   256, 4096, CN, CN);
    tr_f32_h<<<dim3(64, 4, 4), 256, 0, stream>>>(xth, xthT, 256, 4096, CN, CN);

    // all 16 projections, one dispatch (1024 blocks)
    proj_all<<<dim3(2, 32, 16), 512, 0, stream>>>(xT, xthT, wts,
        bk_rgb, bk_th, bv_rgb, bv_th, Kt, Ktth, Vt2, Vt2 + CN, CN);

    tr_h_h<<<dim3(4, 64, 8), 256, 0, stream>>>(Vt2, V2, 4096, 256, CN, CN);

    for (int p = 0; p < 2; ++p) {
        for (int lb = 0; lb < 2; ++lb) {
            int b = 2 * p + lb;
            u16* St = StH + (long)lb * PtE;
            gemm512<1><<<dim3(32, 32, 1), 512, 0, stream>>>(
                Kt + b * CN, 256, 0, Ktth + b * CN, 256, 0, 256, 0, 0, St, 4096, 0);
            colstats_partial<<<dim3(16, 16), 256, 0, stream>>>(St, pmax, psum);
            colstats_combine<<<16, 256, 0, stream>>>(pmax, psum, cmax, crcp);
            pt8_kernel<<<dim3(1, 4096), 512, 0, stream>>>(St, cmax, crcp);
        }
        // x_1 = gamma1 * (V @ P) + x   (z = {lb,t}, 256 blocks)
        gemm_fused<true><<<dim3(32, 2, 4), 512, 0, stream>>>(
            V2 + (long)p * 4 * CN, CN, 4096, StH, PtE, 4096, 4096,
            g1r, g1t, x + 2L * p * CN, xth + 2L * p * CN, CN, 4096,
            outX2 + 2L * p * CN, outXt2 + 2L * p * CN, CN, 4096);

        // energy[c,d] = sum_n Vth[c,n] V[d,n], batched split-K (64 slices of 64)
        (void)hipMemsetAsync(E + 2L * p * 65536, 0, 2 * 65536 * sizeof(float), stream);
        gemm512<2><<<dim3(2, 2, 128), 512, 0, stream>>>(
            V2 + (long)p * 4 * CN + CN, 4096, 2 * CN,
            V2 + (long)p * 4 * CN,      4096, 2 * CN,
            4096, 64, 6, E + 2L * p * 65536, 256, 65536);
        simc_kernel<<<dim3(256, 2), 256, 0, stream>>>(E + 2L * p * 65536, simc + 2L * p * 65536);

        // x_2 = gamma2 * (simc @ V) + x_1   (in-place on d_out)
        gemm_fused<false><<<dim3(32, 2, 4), 512, 0, stream>>>(
            simc + 2L * p * 65536, 65536, 256, Vt2 + (long)p * 4 * CN, CN, 256, 256,
            g2r, g2t, outX2 + 2L * p * CN, outXt2 + 2L * p * CN, CN, 4096,
            outX2 + 2L * p * CN, outXt2 + 2L * p * CN, CN, 4096);
    }
}

// Round 6
// 378.380 us; speedup vs baseline: 4.2035x; 1.9118x over previous
//
#include <hip/hip_runtime.h>

typedef unsigned short u16;
typedef __attribute__((ext_vector_type(8))) _Float16 f16x8;
typedef __attribute__((ext_vector_type(4))) float f32x4;

#define DEVINL __device__ __forceinline__

DEVINL u16 f2h_u(float f) { _Float16 h = (_Float16)f; return __builtin_bit_cast(unsigned short, h); }
DEVINL float h2f_u(u16 h) { return (float)__builtin_bit_cast(_Float16, h); }

DEVINL f16x8 ldfrag(const u16* p) {
    int4 d = *(const int4*)p;                 // ds_read_b128
    return __builtin_bit_cast(f16x8, d);
}

DEVINL void glds16(const u16* g, u16* l) {    // async global->LDS, 16B/lane
    __builtin_amdgcn_global_load_lds(
        (const __attribute__((address_space(1))) unsigned int*)g,
        (__attribute__((address_space(3))) unsigned int*)l, 16, 0, 0);
}

#define CFENCE asm volatile("" ::: "memory")
#define VMCNT8 asm volatile("s_waitcnt vmcnt(8)" ::: "memory")
#define VMCNT0 asm volatile("s_waitcnt vmcnt(0)" ::: "memory")
#define LGKM0  asm volatile("s_waitcnt lgkmcnt(0)" ::: "memory")

// ---------------------------------------------------------------------------
// NT GEMM core v3: C[i,j] = sum_k A[i,k]*B[j,k], fp16 in, f32 accum.
// 256 thr = 4 waves (2x2); block tile 128x128; wave tile 64x64 (4x4 frags);
// BK=64. LDS [128][64] per operand, 2 buffers (64 KB total) -> 2 blocks/CU.
// Swizzle: chunk' = chunk ^ (row&7) (row stride 128B = bank period; spreads a
// wave's b128 reads uniformly 8 lanes/bank-quad). Staged via global_load_lds
// with pre-swizzled per-lane SOURCE, linear LDS dest (rule 21).
// Counted-vmcnt 2-buf pipeline: 8 glds/wave/tile; iter t: vmcnt(8) [tile t
// landed, t+1 in flight] -> bar -> ds_read+MFMA -> lgkm0 -> bar -> stage(t+2).
// ---------------------------------------------------------------------------
DEVINL void gemm_core(const u16* __restrict__ Ag, int lda,
                      const u16* __restrict__ Bg, int ldb,
                      int kOff, int kLen, u16* As, u16* Bs, f32x4 (&acc)[4][4])
{
    int tid = threadIdx.x;
    int lane = tid & 63, w = tid >> 6;
    int wr = w >> 1, wc = w & 1;
    int kg = lane >> 4, rl = lane & 15;
    int l8 = lane >> 3, c8 = lane & 7;

    // staging: wave w stages rows [w*32, +32) of A and B; glds q covers 8 rows
    int srow = w * 32 + l8;
    int scol = (c8 ^ l8) * 8;                      // pre-swizzled source chunk
    const u16* aS = Ag + (size_t)srow * lda + kOff + scol;
    const u16* bS = Bg + (size_t)srow * ldb + kOff + scol;
    int dOff = w * 2048;                           // wave-uniform LDS base (elems)

    int rl7 = rl & 7;
    int e0 = (kg ^ rl7) * 8;                       // kk=0 chunk (swizzled)
    int e1 = e0 ^ 32;                              // kk=1: chunk^4 -> elems^32
    int aRow = (wr * 64 + rl) * 64;
    int bRow = (wc * 64 + rl) * 64;

    int nt = kLen >> 6;                            // requires kLen % 64 == 0, nt >= 2
    // prologue: tiles 0,1 -> bufs 0,1
#pragma unroll
    for (int q = 0; q < 4; ++q) {
        glds16(aS + (size_t)q * 8 * lda, As + dOff + q * 512);
        glds16(bS + (size_t)q * 8 * ldb, Bs + dOff + q * 512);
    }
#pragma unroll
    for (int q = 0; q < 4; ++q) {
        glds16(aS + (size_t)q * 8 * lda + 64, As + 8192 + dOff + q * 512);
        glds16(bS + (size_t)q * 8 * ldb + 64, Bs + 8192 + dOff + q * 512);
    }

    for (int t = 0; t < nt; ++t) {
        const u16* Ab = As + (t & 1) * 8192;
        const u16* Bb = Bs + (t & 1) * 8192;
        if (t + 1 < nt) { VMCNT8; } else { VMCNT0; }
        __builtin_amdgcn_s_barrier();
        CFENCE;
        f16x8 a0[4], b0[4], a1[4], b1[4];
#pragma unroll
        for (int i = 0; i < 4; ++i) a0[i] = ldfrag(&Ab[aRow + i * 1024 + e0]);
#pragma unroll
        for (int i = 0; i < 4; ++i) b0[i] = ldfrag(&Bb[bRow + i * 1024 + e0]);
#pragma unroll
        for (int i = 0; i < 4; ++i) a1[i] = ldfrag(&Ab[aRow + i * 1024 + e1]);
#pragma unroll
        for (int i = 0; i < 4; ++i) b1[i] = ldfrag(&Bb[bRow + i * 1024 + e1]);
        __builtin_amdgcn_s_setprio(1);
#pragma unroll
        for (int i = 0; i < 4; ++i)
#pragma unroll
            for (int j = 0; j < 4; ++j)
                acc[i][j] = __builtin_amdgcn_mfma_f32_16x16x32_f16(a0[i], b0[j], acc[i][j], 0, 0, 0);
#pragma unroll
        for (int i = 0; i < 4; ++i)
#pragma unroll
            for (int j = 0; j < 4; ++j)
                acc[i][j] = __builtin_amdgcn_mfma_f32_16x16x32_f16(a1[i], b1[j], acc[i][j], 0, 0, 0);
        __builtin_amdgcn_s_setprio(0);
        LGKM0;
        __builtin_amdgcn_s_barrier();
        CFENCE;
        if (t + 2 < nt) {
            const u16* aN = aS + (size_t)(t + 2) * 64;
            const u16* bN = bS + (size_t)(t + 2) * 64;
            u16* Ad = As + (t & 1) * 8192 + dOff;
            u16* Bd = Bs + (t & 1) * 8192 + dOff;
#pragma unroll
            for (int q = 0; q < 4; ++q) {
                glds16(aN + (size_t)q * 8 * lda, Ad + q * 512);
                glds16(bN + (size_t)q * 8 * ldb, Bd + q * 512);
            }
        }
    }
}

// EPI: 1 = fp16 store; 2 = split-K atomicAdd f32 (z -> {bq=z>>zshift, slice})
template<int EPI>
__launch_bounds__(256, 2)
__global__ void gemm512(const u16* __restrict__ A, int lda, long sAz,
                        const u16* __restrict__ B, int ldb, long sBz,
                        int K, int splitK, int zshift,
                        void* outv, int ldo, long sOz)
{
    __shared__ __align__(16) u16 As[2 * 8192];
    __shared__ __align__(16) u16 Bs[2 * 8192];
    int z = blockIdx.z;
    int kOff = 0, kLen = K;
    long zo = 0;
    if (EPI == 2) {
        int bq = z >> zshift, s = z & ((1 << zshift) - 1);
        kOff = s * splitK; kLen = splitK;
        A += sAz * bq; B += sBz * bq; zo = sOz * bq;
    } else {
        A += sAz * z; B += sBz * z; zo = sOz * z;
    }
    int rowBase = blockIdx.y * 128, colBase = blockIdx.x * 128;
    f32x4 acc[4][4];
#pragma unroll
    for (int i = 0; i < 4; ++i)
#pragma unroll
        for (int j = 0; j < 4; ++j) acc[i][j] = (f32x4){0.f, 0.f, 0.f, 0.f};

    gemm_core(A + (size_t)rowBase * lda, lda, B + (size_t)colBase * ldb, ldb, kOff, kLen, As, Bs, acc);

    int lane = threadIdx.x & 63, w = threadIdx.x >> 6;
    int wr = w >> 1, wc = w & 1, kg = lane >> 4, rl = lane & 15;
    u16* outh = (u16*)outv;
    float* outf = (float*)outv;
#pragma unroll
    for (int i = 0; i < 4; ++i) {
        int row0 = rowBase + wr * 64 + i * 16 + kg * 4;
#pragma unroll
        for (int j = 0; j < 4; ++j) {
            int col = colBase + wc * 64 + j * 16 + rl;
            f32x4 v = acc[i][j];
#pragma unroll
            for (int r = 0; r < 4; ++r) {
                size_t o = (size_t)(row0 + r) * ldo + col;
                if (EPI == 1) outh[zo + o] = f2h_u(v[r]);
                else atomicAdd(&outf[zo + o], v[r]);
            }
        }
    }
}

// all 16 projections in one dispatch: z = b*4 + t, out[n][o] fp16 + bias
__launch_bounds__(256, 2)
__global__ void proj_all(const u16* __restrict__ xT, const u16* __restrict__ xthT,
                         const u16* __restrict__ wts,
                         const float* __restrict__ b0, const float* __restrict__ b1,
                         const float* __restrict__ b2, const float* __restrict__ b3,
                         u16* o0, u16* o1, u16* o2, u16* o3, long CN)
{
    __shared__ __align__(16) u16 As[2 * 8192];
    __shared__ __align__(16) u16 Bs[2 * 8192];
    int z = blockIdx.z, b = z >> 2, t = z & 3;
    const u16* A = ((t & 1) ? xthT : xT) + (long)b * CN;
    const u16* B = wts + t * 65536;
    u16* out = t == 0 ? o0 + (long)b * CN : t == 1 ? o1 + (long)b * CN
             : t == 2 ? o2 + (long)b * 2 * CN : o3 + (long)b * 2 * CN;
    int rowBase = blockIdx.y * 128, colBase = blockIdx.x * 128;
    f32x4 acc[4][4];
#pragma unroll
    for (int i = 0; i < 4; ++i)
#pragma unroll
        for (int j = 0; j < 4; ++j) acc[i][j] = (f32x4){0.f, 0.f, 0.f, 0.f};

    gemm_core(A + (size_t)rowBase * 256, 256, B + (size_t)colBase * 256, 256, 0, 256, As, Bs, acc);

    const float* bias = t == 0 ? b0 : t == 1 ? b1 : t == 2 ? b2 : b3;
    int lane = threadIdx.x & 63, w = threadIdx.x >> 6;
    int wr = w >> 1, wc = w & 1, kg = lane >> 4, rl = lane & 15;
#pragma unroll
    for (int i = 0; i < 4; ++i) {
        int row0 = rowBase + wr * 64 + i * 16 + kg * 4;
#pragma unroll
        for (int j = 0; j < 4; ++j) {
            int col = colBase + wc * 64 + j * 16 + rl;
            f32x4 v = acc[i][j];
#pragma unroll
            for (int r = 0; r < 4; ++r)
                out[(size_t)(row0 + r) * 256 + col] = f2h_u(v[r] + bias[col]);
        }
    }
}

// Fused apply GEMM: out = gamma*(A.B^T) + src, z = {bb = z>>1, t = z&1}.
// APERZ: A indexed by z (PV), else by bb (channel; B by z).
template<bool APERZ>
__launch_bounds__(256, 2)
__global__ void gemm_fused(const u16* __restrict__ Ab, long sA, int lda,
                           const u16* __restrict__ Bb, long sB, int ldb, int K,
                           const float* __restrict__ g0p, const float* __restrict__ g1p,
                           const float* src0, const float* src1, long sS, int ldsrc,
                           float* out0, float* out1, long sO, int ldo)
{
    __shared__ __align__(16) u16 As[2 * 8192];
    __shared__ __align__(16) u16 Bs[2 * 8192];
    int z = blockIdx.z, bb = z >> 1, t = z & 1;
    const u16* A = Ab + (APERZ ? (long)z : (long)bb) * sA;
    const u16* B = Bb + (APERZ ? (long)bb : (long)z) * sB;
    const float* src = (t ? src1 : src0) + (long)bb * sS;
    float* out = (t ? out1 : out0) + (long)bb * sO;

    int rowBase = blockIdx.y * 128, colBase = blockIdx.x * 128;
    f32x4 acc[4][4];
#pragma unroll
    for (int i = 0; i < 4; ++i)
#pragma unroll
        for (int j = 0; j < 4; ++j) acc[i][j] = (f32x4){0.f, 0.f, 0.f, 0.f};

    gemm_core(A + (size_t)rowBase * lda, lda, B + (size_t)colBase * ldb, ldb, 0, K, As, Bs, acc);

    float gamma = t ? *g1p : *g0p;     // after core: keeps in-loop vmcnt exact
    int lane = threadIdx.x & 63, w = threadIdx.x >> 6;
    int wr = w >> 1, wc = w & 1, kg = lane >> 4, rl = lane & 15;
#pragma unroll
    for (int i = 0; i < 4; ++i) {
        int row0 = rowBase + wr * 64 + i * 16 + kg * 4;
#pragma unroll
        for (int j = 0; j < 4; ++j) {
            int col = colBase + wc * 64 + j * 16 + rl;
            f32x4 v = acc[i][j];
#pragma unroll
            for (int r = 0; r < 4; ++r) {
                int row = row0 + r;
                out[(size_t)row * ldo + col] = gamma * v[r] + src[(size_t)row * ldsrc + col];
            }
        }
    }
}

// f32 [R][NC] -> fp16 [NC][R] transpose (64x64 LDS tiles)
__global__ void tr_f32_h(const float* __restrict__ in, u16* __restrict__ out,
                         int R, int NC_, long sIn, long sOut)
{
    in += (long)blockIdx.z * sIn; out += (long)blockIdx.z * sOut;
    __shared__ u16 s[64 * 65];
    int tx = threadIdx.x & 63, tw = threadIdx.x >> 6;
    int r0 = blockIdx.y * 64, c0 = blockIdx.x * 64;
#pragma unroll
    for (int p = 0; p < 16; ++p) {
        int r = tw + p * 4;
        s[tx * 65 + r] = f2h_u(in[(size_t)(r0 + r) * NC_ + c0 + tx]);
    }
    __syncthreads();
#pragma unroll
    for (int p = 0; p < 16; ++p) {
        int rr = tw + p * 4;
        out[(size_t)(c0 + rr) * R + r0 + tx] = s[rr * 65 + tx];
    }
}

// fp16 [R][NC] -> fp16 [NC][R]
__global__ void tr_h_h(const u16* __restrict__ in, u16* __restrict__ out,
                       int R, int NC_, long sIn, long sOut)
{
    in += (long)blockIdx.z * sIn; out += (long)blockIdx.z * sOut;
    __shared__ u16 s[64 * 65];
    int tx = threadIdx.x & 63, tw = threadIdx.x >> 6;
    int r0 = blockIdx.y * 64, c0 = blockIdx.x * 64;
#pragma unroll
    for (int p = 0; p < 16; ++p) {
        int r = tw + p * 4;
        s[tx * 65 + r] = in[(size_t)(r0 + r) * NC_ + c0 + tx];
    }
    __syncthreads();
#pragma unroll
    for (int p = 0; p < 16; ++p) {
        int rr = tw + p * 4;
        out[(size_t)(c0 + rr) * R + r0 + tx] = s[rr * 65 + tx];
    }
}

__global__ void cvt_w_kernel(const float* __restrict__ w0, const float* __restrict__ w1,
                             const float* __restrict__ w2, const float* __restrict__ w3,
                             u16* __restrict__ out)
{
    int i = blockIdx.x * 256 + threadIdx.x;
    const float* w = (i < 65536) ? w0 : (i < 131072) ? w1 : (i < 196608) ? w2 : w3;
    out[i] = f2h_u(w[i & 65535]);
}

// column-wise (over m) online max/sum-exp partials of fp16 St[b][4096][4096]
__global__ void colstats_partial(const u16* __restrict__ St,
                                 float* __restrict__ pmax, float* __restrict__ psum)
{
    int b = blockIdx.z;
    St += (long)b * 4096L * 4096L;
    int col = blockIdx.x * 256 + threadIdx.x;
    int m0 = blockIdx.y * 256;
    float mx = -3.0e38f, sm = 0.f;
    for (int m = 0; m < 256; ++m) {
        float v = h2f_u(St[(size_t)(m0 + m) * 4096 + col]);
        if (v > mx) { sm = sm * __expf(mx - v) + 1.f; mx = v; }
        else sm += __expf(v - mx);
    }
    pmax[b * 65536 + blockIdx.y * 4096 + col] = mx;
    psum[b * 65536 + blockIdx.y * 4096 + col] = sm;
}

__global__ void colstats_combine(const float* __restrict__ pmax, const float* __restrict__ psum,
                                 float* __restrict__ cmax, float* __restrict__ crcp)
{
    int b = blockIdx.y;
    int col = blockIdx.x * 256 + threadIdx.x;
    float mx = -3.0e38f;
    for (int i = 0; i < 16; ++i) mx = fmaxf(mx, pmax[b * 65536 + i * 4096 + col]);
    float s = 0.f;
    for (int i = 0; i < 16; ++i) s += psum[b * 65536 + i * 4096 + col] * __expf(pmax[b * 65536 + i * 4096 + col] - mx);
    cmax[b * 4096 + col] = mx;
    crcp[b * 4096 + col] = 1.f / s;
}

// in-place Pt[m,n] = fp16( exp(St[m,n]-cmax[n]) * crcp[n] ), 8 cols/thread
__global__ void pt8_kernel(u16* St, const float* __restrict__ cmax,
                           const float* __restrict__ crcp)
{
    int b = blockIdx.z;
    St += (long)b * 4096L * 4096L;
    cmax += b * 4096; crcp += b * 4096;
    int m = blockIdx.y;
    int c0 = (blockIdx.x * 256 + threadIdx.x) * 8;
    size_t o = (size_t)m * 4096 + c0;
    f16x8 hv = __builtin_bit_cast(f16x8, *(const int4*)(St + o));
    union { u16 q[8]; int4 v; } pk;
#pragma unroll
    for (int j = 0; j < 8; ++j)
        pk.q[j] = f2h_u(__expf((float)hv[j] - cmax[c0 + j]) * crcp[c0 + j]);
    *(int4*)(St + o) = pk.v;
}

DEVINL float blockReduce(float v, int op) {  // op 0 = max, 1 = sum; 256 threads
    __shared__ float s[4];
#pragma unroll
    for (int o = 32; o; o >>= 1) {
        float t = __shfl_xor(v, o, 64);
        v = op ? (v + t) : fmaxf(v, t);
    }
    __syncthreads();
    if ((threadIdx.x & 63) == 0) s[threadIdx.x >> 6] = v;
    __syncthreads();
    return op ? (s[0] + s[1] + s[2] + s[3]) : fmaxf(fmaxf(s[0], s[1]), fmaxf(s[2], s[3]));
}

// sim_c row softmax of (rowmax(E) - E) over d; E f32 [b][256][256]
__global__ void simc_kernel(const float* __restrict__ E, u16* __restrict__ simc)
{
    int bb = blockIdx.y;
    const float* Eb = E + bb * 65536;
    u16* sc = simc + bb * 65536;
    int c = blockIdx.x, d = threadIdx.x;
    float e = Eb[c * 256 + d];
    float rmax = blockReduce(e, 0);
    float v = rmax - e;
    float vmax = blockReduce(v, 0);
    float p = __expf(v - vmax);
    float s = blockReduce(p, 1);
    sc[c * 256 + d] = f2h_u(p / s);
}

extern "C" void kernel_launch(void* const* d_in, const int* in_sizes, int n_in,
                              void* d_out, int out_size, void* d_ws, size_t ws_size,
                              hipStream_t stream)
{
    const float* x      = (const float*)d_in[0];
    const float* xth    = (const float*)d_in[1];
    const float* Wk_rgb = (const float*)d_in[2];
    const float* bk_rgb = (const float*)d_in[3];
    const float* Wk_th  = (const float*)d_in[4];
    const float* bk_th  = (const float*)d_in[5];
    const float* Wv_rgb = (const float*)d_in[6];
    const float* bv_rgb = (const float*)d_in[7];
    const float* Wv_th  = (const float*)d_in[8];
    const float* bv_th  = (const float*)d_in[9];
    const float* g1r = (const float*)d_in[10];
    const float* g1t = (const float*)d_in[11];
    const float* g2r = (const float*)d_in[12];
    const float* g2t = (const float*)d_in[13];

    const long CN = 256L * 4096L;        // 1M elems per batch-tensor
    const long PtE = 4096L * 4096L;      // 16M elems

    // ws carve-up (~176.5 MB)
    u16* wts   = (u16*)d_ws;             // [4][256][256] fp16
    u16* Kt    = wts + 4 * 65536;        // [4][4096][256] x_k^T  (dead after St GEMM)
    u16* Ktth  = Kt + 4 * CN;
    u16* Vt2   = Ktth + 4 * CN;          // [4][2][4096][256] (t=0: x_v^T, 1: x_v_th^T)
    u16* V2    = Vt2 + 8 * CN;           // [4][2][256][4096]
    u16* StH   = V2 + 8 * CN;            // [4][4096][4096] fp16 St -> Pt in place (128 MB)
    // stats alias the dead Kt region (Kt only read by the St GEMM, which
    // completes before any of these are written)
    u16* simc   = Kt;                    // [4][256][256] fp16
    float* E    = (float*)(Kt + 4 * 65536);  // [4][256][256] f32
    float* pmax = E + 4 * 65536;         // [4][16][4096]
    float* psum = pmax + 4 * 65536;
    float* cmax = psum + 4 * 65536;      // [4][4096]
    float* crcp = cmax + 4 * 4096;
    u16* xT    = StH;                    // alias: dead before first StH write
    u16* xthT  = xT + 4 * CN;

    float* outX2  = (float*)d_out;
    float* outXt2 = outX2 + 4 * CN;

    cvt_w_kernel<<<1024, 256, 0, stream>>>(Wk_rgb, Wk_th, Wv_rgb, Wv_th, wts);
    tr_f32_h<<<dim3(64, 4, 4), 256, 0, stream>>>(x,   xT,   256, 4096, CN, CN);
    tr_f32_h<<<dim3(64, 4, 4), 256, 0, stream>>>(xth, xthT, 256, 4096, CN, CN);

    // all 16 projections, one dispatch (1024 blocks, 2/CU)
    proj_all<<<dim3(2, 32, 16), 256, 0, stream>>>(xT, xthT, wts,
        bk_rgb, bk_th, bv_rgb, bv_th, Kt, Ktth, Vt2, Vt2 + CN, CN);

    tr_h_h<<<dim3(4, 64, 8), 256, 0, stream>>>(Vt2, V2, 4096, 256, CN, CN);

    // St[b][m][n] = sum_c Kt[b][m][c] * Ktth[b][n][c]  (one z=4 dispatch)
    gemm512<1><<<dim3(32, 32, 4), 256, 0, stream>>>(
        Kt, 256, CN, Ktth, 256, CN, 256, 0, 0, StH, 4096, PtE);

    colstats_partial<<<dim3(16, 16, 4), 256, 0, stream>>>(StH, pmax, psum);
    colstats_combine<<<dim3(16, 4), 256, 0, stream>>>(pmax, psum, cmax, crcp);
    pt8_kernel<<<dim3(2, 4096, 4), 256, 0, stream>>>(StH, cmax, crcp);

    // x_1 = gamma1 * (V @ P) + x   (z = {b,t}: 512 blocks, 2/CU)
    gemm_fused<true><<<dim3(32, 2, 8), 256, 0, stream>>>(
        V2, CN, 4096, StH, PtE, 4096, 4096,
        g1r, g1t, x, xth, CN, 4096,
        outX2, outXt2, CN, 4096);

    // energy[c,d] = sum_n Vth[c,n] V[d,n]; split-K (32 slices of 128) x 4 batches
    (void)hipMemsetAsync(E, 0, 4 * 65536 * sizeof(float), stream);
    gemm512<2><<<dim3(2, 2, 128), 256, 0, stream>>>(
        V2 + CN, 4096, 2 * CN, V2, 4096, 2 * CN,
        4096, 128, 5, E, 256, 65536);
    simc_kernel<<<dim3(256, 4), 256, 0, stream>>>(E, simc);

    // x_2 = gamma2 * (simc @ V) + x_1   (in-place on d_out, 512 blocks)
    gemm_fused<false><<<dim3(32, 2, 8), 256, 0, stream>>>(
        simc, 65536, 256, Vt2, CN, 256, 256,
        g2r, g2t, outX2, outXt2, CN, 4096,
        outX2, outXt2, CN, 4096);
}

// Round 7
// 270.220 us; speedup vs baseline: 5.8861x; 1.4003x over previous
//
#include <hip/hip_runtime.h>

typedef unsigned short u16;
typedef __attribute__((ext_vector_type(8))) _Float16 f16x8;
typedef __attribute__((ext_vector_type(4))) float f32x4;

#define DEVINL __device__ __forceinline__

DEVINL u16 f2h_u(float f) { _Float16 h = (_Float16)f; return __builtin_bit_cast(unsigned short, h); }
DEVINL float h2f_u(u16 h) { return (float)__builtin_bit_cast(_Float16, h); }

DEVINL f16x8 ldfrag(const u16* p) {
    int4 d = *(const int4*)p;                 // ds_read_b128
    return __builtin_bit_cast(f16x8, d);
}

DEVINL void glds16(const u16* g, u16* l) {    // async global->LDS, 16B/lane
    __builtin_amdgcn_global_load_lds(
        (const __attribute__((address_space(1))) unsigned int*)g,
        (__attribute__((address_space(3))) unsigned int*)l, 16, 0, 0);
}

#define CFENCE asm volatile("" ::: "memory")
#define VMCNT8 asm volatile("s_waitcnt vmcnt(8)" ::: "memory")
#define VMCNT0 asm volatile("s_waitcnt vmcnt(0)" ::: "memory")
#define LGKM0  asm volatile("s_waitcnt lgkmcnt(0)" ::: "memory")

static const long CN  = 256L * 4096L;   // 1M elems per batch-tensor
static const long PtE = 4096L * 4096L;  // 16M elems

// ---------------------------------------------------------------------------
// NT GEMM core v3 (round 6, unchanged): 256 thr = 4 waves (2x2); block tile
// 128x128; wave 64x64; BK=64; 2-buf counted-vmcnt pipeline; 3-bit chunk-XOR
// swizzle (0 bank conflicts measured).
// ---------------------------------------------------------------------------
DEVINL void gemm_core(const u16* __restrict__ Ag, int lda,
                      const u16* __restrict__ Bg, int ldb,
                      int kOff, int kLen, u16* As, u16* Bs, f32x4 (&acc)[4][4])
{
    int tid = threadIdx.x;
    int lane = tid & 63, w = tid >> 6;
    int wr = w >> 1, wc = w & 1;
    int kg = lane >> 4, rl = lane & 15;
    int l8 = lane >> 3, c8 = lane & 7;

    int srow = w * 32 + l8;
    int scol = (c8 ^ l8) * 8;                      // pre-swizzled source chunk
    const u16* aS = Ag + (size_t)srow * lda + kOff + scol;
    const u16* bS = Bg + (size_t)srow * ldb + kOff + scol;
    int dOff = w * 2048;

    int rl7 = rl & 7;
    int e0 = (kg ^ rl7) * 8;
    int e1 = e0 ^ 32;
    int aRow = (wr * 64 + rl) * 64;
    int bRow = (wc * 64 + rl) * 64;

    int nt = kLen >> 6;                            // kLen % 64 == 0, nt >= 2
#pragma unroll
    for (int q = 0; q < 4; ++q) {
        glds16(aS + (size_t)q * 8 * lda, As + dOff + q * 512);
        glds16(bS + (size_t)q * 8 * ldb, Bs + dOff + q * 512);
    }
#pragma unroll
    for (int q = 0; q < 4; ++q) {
        glds16(aS + (size_t)q * 8 * lda + 64, As + 8192 + dOff + q * 512);
        glds16(bS + (size_t)q * 8 * ldb + 64, Bs + 8192 + dOff + q * 512);
    }

    for (int t = 0; t < nt; ++t) {
        const u16* Ab = As + (t & 1) * 8192;
        const u16* Bb = Bs + (t & 1) * 8192;
        if (t + 1 < nt) { VMCNT8; } else { VMCNT0; }
        __builtin_amdgcn_s_barrier();
        CFENCE;
        f16x8 a0[4], b0[4], a1[4], b1[4];
#pragma unroll
        for (int i = 0; i < 4; ++i) a0[i] = ldfrag(&Ab[aRow + i * 1024 + e0]);
#pragma unroll
        for (int i = 0; i < 4; ++i) b0[i] = ldfrag(&Bb[bRow + i * 1024 + e0]);
#pragma unroll
        for (int i = 0; i < 4; ++i) a1[i] = ldfrag(&Ab[aRow + i * 1024 + e1]);
#pragma unroll
        for (int i = 0; i < 4; ++i) b1[i] = ldfrag(&Bb[bRow + i * 1024 + e1]);
        __builtin_amdgcn_s_setprio(1);
#pragma unroll
        for (int i = 0; i < 4; ++i)
#pragma unroll
            for (int j = 0; j < 4; ++j)
                acc[i][j] = __builtin_amdgcn_mfma_f32_16x16x32_f16(a0[i], b0[j], acc[i][j], 0, 0, 0);
#pragma unroll
        for (int i = 0; i < 4; ++i)
#pragma unroll
            for (int j = 0; j < 4; ++j)
                acc[i][j] = __builtin_amdgcn_mfma_f32_16x16x32_f16(a1[i], b1[j], acc[i][j], 0, 0, 0);
        __builtin_amdgcn_s_setprio(0);
        LGKM0;
        __builtin_amdgcn_s_barrier();
        CFENCE;
        if (t + 2 < nt) {
            const u16* aN = aS + (size_t)(t + 2) * 64;
            const u16* bN = bS + (size_t)(t + 2) * 64;
            u16* Ad = As + (t & 1) * 8192 + dOff;
            u16* Bd = Bs + (t & 1) * 8192 + dOff;
#pragma unroll
            for (int q = 0; q < 4; ++q) {
                glds16(aN + (size_t)q * 8 * lda, Ad + q * 512);
                glds16(bN + (size_t)q * 8 * ldb, Bd + q * 512);
            }
        }
    }
}

DEVINL void mergeMS(float& m, float& s, float om, float os) {
    float nm = fmaxf(m, om);
    s = s * __expf(m - nm) + os * __expf(om - nm);
    m = nm;
}

// ---------------------------------------------------------------------------
// St GEMM + fused column-stats epilogue. Flat grid 4096, XCD-swizzled:
// L = (P&7)*512 + P>>3;  b = L>>10, yb = (L>>5)&31, xb = L&31.
// Per-XCD chunk = 16 yb x 32 xb of one batch -> A+B working set ~3MB < L2.
// Stats: per-column (max, sumexp) over this block's 128 rows, computed from
// the fp16-ROUNDED store values (self-consistent with pt8), reduced over
// kg (shfl) and wr (LDS), written to pmax/psum[b][yb][col] (d_out scratch).
// ---------------------------------------------------------------------------
__launch_bounds__(256, 2)
__global__ void st_gemm(const u16* __restrict__ Kt, const u16* __restrict__ Ktth,
                        u16* __restrict__ StH,
                        float* __restrict__ pmax, float* __restrict__ psum)
{
    __shared__ __align__(16) u16 As[2 * 8192];
    __shared__ __align__(16) u16 Bs[2 * 8192];
    int P = blockIdx.x;
    int L = (P & 7) * 512 + (P >> 3);
    int b = L >> 10, yb = (L >> 5) & 31, xb = L & 31;
    const u16* A = Kt   + (long)b * CN + (size_t)yb * 128 * 256;
    const u16* B = Ktth + (long)b * CN + (size_t)xb * 128 * 256;
    u16* out = StH + (long)b * PtE;
    int rowBase = yb * 128, colBase = xb * 128;

    f32x4 acc[4][4];
#pragma unroll
    for (int i = 0; i < 4; ++i)
#pragma unroll
        for (int j = 0; j < 4; ++j) acc[i][j] = (f32x4){0.f, 0.f, 0.f, 0.f};

    gemm_core(A, 256, B, 256, 0, 256, As, Bs, acc);

    int lane = threadIdx.x & 63, w = threadIdx.x >> 6;
    int wr = w >> 1, wc = w & 1, kg = lane >> 4, rl = lane & 15;

    float tm[4], ts[4];
#pragma unroll
    for (int j = 0; j < 4; ++j) { tm[j] = -3.0e38f; ts[j] = 0.f; }

#pragma unroll
    for (int i = 0; i < 4; ++i) {
        int row0 = rowBase + wr * 64 + i * 16 + kg * 4;
#pragma unroll
        for (int j = 0; j < 4; ++j) {
            int col = colBase + wc * 64 + j * 16 + rl;
            f32x4 v = acc[i][j];
#pragma unroll
            for (int r = 0; r < 4; ++r) {
                u16 h = f2h_u(v[r]);
                out[(size_t)(row0 + r) * 4096 + col] = h;
                float x = h2f_u(h);
                float nm = fmaxf(tm[j], x);
                ts[j] = ts[j] * __expf(tm[j] - nm) + __expf(x - nm);
                tm[j] = nm;
            }
        }
    }
    // merge across kg groups (rows) via shfl butterfly
#pragma unroll
    for (int j = 0; j < 4; ++j) {
        mergeMS(tm[j], ts[j], __shfl_xor(tm[j], 16, 64), __shfl_xor(ts[j], 16, 64));
        mergeMS(tm[j], ts[j], __shfl_xor(tm[j], 32, 64), __shfl_xor(ts[j], 32, 64));
    }
    // merge across wr via LDS (As is free after core)
    float* red = (float*)As;              // [2 wc][4 j][16 rl][2]
    __syncthreads();
    if (wr == 1 && lane < 16) {
#pragma unroll
        for (int j = 0; j < 4; ++j) {
            red[((wc * 4 + j) * 16 + rl) * 2 + 0] = tm[j];
            red[((wc * 4 + j) * 16 + rl) * 2 + 1] = ts[j];
        }
    }
    __syncthreads();
    if (wr == 0 && lane < 16) {
#pragma unroll
        for (int j = 0; j < 4; ++j) {
            mergeMS(tm[j], ts[j], red[((wc * 4 + j) * 16 + rl) * 2 + 0],
                                  red[((wc * 4 + j) * 16 + rl) * 2 + 1]);
            int col = colBase + wc * 64 + j * 16 + rl;
            long idx = ((long)b * 32 + yb) * 4096 + col;
            pmax[idx] = tm[j];
            psum[idx] = ts[j];
        }
    }
}

// fold 32 row-block partials -> cmax, crcp
__global__ void stats_combine(const float* __restrict__ pmax, const float* __restrict__ psum,
                              float* __restrict__ cmax, float* __restrict__ crcp)
{
    int b = blockIdx.y;
    int col = blockIdx.x * 256 + threadIdx.x;
    const float* pm = pmax + (long)b * 32 * 4096 + col;
    const float* ps = psum + (long)b * 32 * 4096 + col;
    float m = -3.0e38f, s = 0.f;
    for (int i = 0; i < 32; ++i) mergeMS(m, s, pm[i * 4096], ps[i * 4096]);
    cmax[b * 4096 + col] = m;
    crcp[b * 4096 + col] = 1.f / s;
}

// EPI 2 = split-K atomicAdd f32 (z -> {bq=z>>zshift, slice}) -- energy only
template<int EPI>
__launch_bounds__(256, 2)
__global__ void gemm512(const u16* __restrict__ A, int lda, long sAz,
                        const u16* __restrict__ B, int ldb, long sBz,
                        int K, int splitK, int zshift,
                        void* outv, int ldo, long sOz)
{
    __shared__ __align__(16) u16 As[2 * 8192];
    __shared__ __align__(16) u16 Bs[2 * 8192];
    int z = blockIdx.z;
    int bq = z >> zshift, s = z & ((1 << zshift) - 1);
    int kOff = s * splitK, kLen = splitK;
    A += sAz * bq; B += sBz * bq;
    long zo = sOz * bq;
    int rowBase = blockIdx.y * 128, colBase = blockIdx.x * 128;
    f32x4 acc[4][4];
#pragma unroll
    for (int i = 0; i < 4; ++i)
#pragma unroll
        for (int j = 0; j < 4; ++j) acc[i][j] = (f32x4){0.f, 0.f, 0.f, 0.f};

    gemm_core(A + (size_t)rowBase * lda, lda, B + (size_t)colBase * ldb, ldb, kOff, kLen, As, Bs, acc);

    int lane = threadIdx.x & 63, w = threadIdx.x >> 6;
    int wr = w >> 1, wc = w & 1, kg = lane >> 4, rl = lane & 15;
    float* outf = (float*)outv;
#pragma unroll
    for (int i = 0; i < 4; ++i) {
        int row0 = rowBase + wr * 64 + i * 16 + kg * 4;
#pragma unroll
        for (int j = 0; j < 4; ++j) {
            int col = colBase + wc * 64 + j * 16 + rl;
            f32x4 v = acc[i][j];
#pragma unroll
            for (int r = 0; r < 4; ++r) {
                size_t o = (size_t)(row0 + r) * ldo + col;
                atomicAdd(&outf[zo + o], v[r]);
            }
        }
    }
}

// all 16 projections in one dispatch: z = b*4 + t, out[n][o] fp16 + bias
__launch_bounds__(256, 2)
__global__ void proj_all(const u16* __restrict__ xT, const u16* __restrict__ xthT,
                         const u16* __restrict__ wts,
                         const float* __restrict__ b0, const float* __restrict__ b1,
                         const float* __restrict__ b2, const float* __restrict__ b3,
                         u16* o0, u16* o1, u16* o2, u16* o3)
{
    __shared__ __align__(16) u16 As[2 * 8192];
    __shared__ __align__(16) u16 Bs[2 * 8192];
    int z = blockIdx.z, b = z >> 2, t = z & 3;
    const u16* A = ((t & 1) ? xthT : xT) + (long)b * CN;
    const u16* B = wts + t * 65536;
    u16* out = t == 0 ? o0 + (long)b * CN : t == 1 ? o1 + (long)b * CN
             : t == 2 ? o2 + (long)b * 2 * CN : o3 + (long)b * 2 * CN;
    int rowBase = blockIdx.y * 128, colBase = blockIdx.x * 128;
    f32x4 acc[4][4];
#pragma unroll
    for (int i = 0; i < 4; ++i)
#pragma unroll
        for (int j = 0; j < 4; ++j) acc[i][j] = (f32x4){0.f, 0.f, 0.f, 0.f};

    gemm_core(A + (size_t)rowBase * 256, 256, B + (size_t)colBase * 256, 256, 0, 256, As, Bs, acc);

    const float* bias = t == 0 ? b0 : t == 1 ? b1 : t == 2 ? b2 : b3;
    int lane = threadIdx.x & 63, w = threadIdx.x >> 6;
    int wr = w >> 1, wc = w & 1, kg = lane >> 4, rl = lane & 15;
#pragma unroll
    for (int i = 0; i < 4; ++i) {
        int row0 = rowBase + wr * 64 + i * 16 + kg * 4;
#pragma unroll
        for (int j = 0; j < 4; ++j) {
            int col = colBase + wc * 64 + j * 16 + rl;
            f32x4 v = acc[i][j];
#pragma unroll
            for (int r = 0; r < 4; ++r)
                out[(size_t)(row0 + r) * 256 + col] = f2h_u(v[r] + bias[col]);
        }
    }
}

// ---------------------------------------------------------------------------
// Fused apply GEMM, flat XCD-swizzled grid (512 blocks).
// MODE 0 (PV):      L = (P&7)*64 + P>>3; b=L>>7, n=(L>>2)&31, y=(L>>1)&1, t=L&1
//   -> the 4 sharers (y,t) of each Pt panel are L-consecutive -> same XCD.
// MODE 1 (channel): b=L>>7, t=(L>>6)&1, n=(L>>1)&31, y=L&1
//   -> per-XCD chunk pins one 2MB Vt2[b][t] panel in L2.
// out = gamma*(A.B^T) + src
// ---------------------------------------------------------------------------
template<int MODE>
__launch_bounds__(256, 2)
__global__ void gemm_fused(const u16* __restrict__ Abase, const u16* __restrict__ Bbase,
                           const float* __restrict__ g0p, const float* __restrict__ g1p,
                           const float* __restrict__ src0, const float* __restrict__ src1,
                           float* __restrict__ out0, float* __restrict__ out1)
{
    __shared__ __align__(16) u16 As[2 * 8192];
    __shared__ __align__(16) u16 Bs[2 * 8192];
    int P = blockIdx.x;
    int L = (P & 7) * 64 + (P >> 3);
    int b, n, y, t;
    const u16 *A, *B;
    int lda, ldb, K;
    if (MODE == 0) {
        b = L >> 7; n = (L >> 2) & 31; y = (L >> 1) & 1; t = L & 1;
        A = Abase + ((long)b * 2 + t) * CN;  lda = 4096;   // V2[b][t]
        B = Bbase + (long)b * PtE;           ldb = 4096;   // Pt[b]
        K = 4096;
    } else {
        b = L >> 7; t = (L >> 6) & 1; n = (L >> 1) & 31; y = L & 1;
        A = Abase + (long)b * 65536;         lda = 256;    // simc[b]
        B = Bbase + ((long)b * 2 + t) * CN;  ldb = 256;    // Vt2[b][t]
        K = 256;
    }
    const float* src = (t ? src1 : src0) + (long)b * CN;
    float* out = (t ? out1 : out0) + (long)b * CN;
    int rowBase = y * 128, colBase = n * 128;

    f32x4 acc[4][4];
#pragma unroll
    for (int i = 0; i < 4; ++i)
#pragma unroll
        for (int j = 0; j < 4; ++j) acc[i][j] = (f32x4){0.f, 0.f, 0.f, 0.f};

    gemm_core(A + (size_t)rowBase * lda, lda, B + (size_t)colBase * ldb, ldb, 0, K, As, Bs, acc);

    float gamma = t ? *g1p : *g0p;     // after core: keeps in-loop vmcnt exact
    int lane = threadIdx.x & 63, w = threadIdx.x >> 6;
    int wr = w >> 1, wc = w & 1, kg = lane >> 4, rl = lane & 15;
#pragma unroll
    for (int i = 0; i < 4; ++i) {
        int row0 = rowBase + wr * 64 + i * 16 + kg * 4;
#pragma unroll
        for (int j = 0; j < 4; ++j) {
            int col = colBase + wc * 64 + j * 16 + rl;
            f32x4 v = acc[i][j];
#pragma unroll
            for (int r = 0; r < 4; ++r) {
                int row = row0 + r;
                out[(size_t)row * 4096 + col] = gamma * v[r] + src[(size_t)row * 4096 + col];
            }
        }
    }
}

// f32 [R][NC] -> fp16 [NC][R] transpose; z = 2 tensors x 4 batches
__global__ void tr_f32_h2(const float* __restrict__ in0, const float* __restrict__ in1,
                          u16* __restrict__ out0, u16* __restrict__ out1)
{
    int z = blockIdx.z, b = z & 3;
    const float* in = ((z >> 2) ? in1 : in0) + (long)b * CN;
    u16* out = ((z >> 2) ? out1 : out0) + (long)b * CN;
    __shared__ u16 s[64 * 65];
    int tx = threadIdx.x & 63, tw = threadIdx.x >> 6;
    int r0 = blockIdx.y * 64, c0 = blockIdx.x * 64;
#pragma unroll
    for (int p = 0; p < 16; ++p) {
        int r = tw + p * 4;
        s[tx * 65 + r] = f2h_u(in[(size_t)(r0 + r) * 4096 + c0 + tx]);
    }
    __syncthreads();
#pragma unroll
    for (int p = 0; p < 16; ++p) {
        int rr = tw + p * 4;
        out[(size_t)(c0 + rr) * 256 + r0 + tx] = s[rr * 65 + tx];
    }
}

// fp16 [R][NC] -> fp16 [NC][R]
__global__ void tr_h_h(const u16* __restrict__ in, u16* __restrict__ out,
                       int R, int NC_, long sIn, long sOut)
{
    in += (long)blockIdx.z * sIn; out += (long)blockIdx.z * sOut;
    __shared__ u16 s[64 * 65];
    int tx = threadIdx.x & 63, tw = threadIdx.x >> 6;
    int r0 = blockIdx.y * 64, c0 = blockIdx.x * 64;
#pragma unroll
    for (int p = 0; p < 16; ++p) {
        int r = tw + p * 4;
        s[tx * 65 + r] = in[(size_t)(r0 + r) * NC_ + c0 + tx];
    }
    __syncthreads();
#pragma unroll
    for (int p = 0; p < 16; ++p) {
        int rr = tw + p * 4;
        out[(size_t)(c0 + rr) * R + r0 + tx] = s[rr * 65 + tx];
    }
}

__global__ void cvt_w_kernel(const float* __restrict__ w0, const float* __restrict__ w1,
                             const float* __restrict__ w2, const float* __restrict__ w3,
                             u16* __restrict__ out)
{
    int i = blockIdx.x * 256 + threadIdx.x;
    const float* w = (i < 65536) ? w0 : (i < 131072) ? w1 : (i < 196608) ? w2 : w3;
    out[i] = f2h_u(w[i & 65535]);
}

// in-place Pt[m,n] = fp16( exp(St[m,n]-cmax[n]) * crcp[n] ), 8 cols/thread
__global__ void pt8_kernel(u16* St, const float* __restrict__ cmax,
                           const float* __restrict__ crcp)
{
    int b = blockIdx.z;
    St += (long)b * PtE;
    cmax += b * 4096; crcp += b * 4096;
    int m = blockIdx.y;
    int c0 = (blockIdx.x * 256 + threadIdx.x) * 8;
    size_t o = (size_t)m * 4096 + c0;
    f16x8 hv = __builtin_bit_cast(f16x8, *(const int4*)(St + o));
    union { u16 q[8]; int4 v; } pk;
#pragma unroll
    for (int j = 0; j < 8; ++j)
        pk.q[j] = f2h_u(__expf((float)hv[j] - cmax[c0 + j]) * crcp[c0 + j]);
    *(int4*)(St + o) = pk.v;
}

DEVINL float blockReduce(float v, int op) {  // op 0 = max, 1 = sum; 256 threads
    __shared__ float s[4];
#pragma unroll
    for (int o = 32; o; o >>= 1) {
        float t = __shfl_xor(v, o, 64);
        v = op ? (v + t) : fmaxf(v, t);
    }
    __syncthreads();
    if ((threadIdx.x & 63) == 0) s[threadIdx.x >> 6] = v;
    __syncthreads();
    return op ? (s[0] + s[1] + s[2] + s[3]) : fmaxf(fmaxf(s[0], s[1]), fmaxf(s[2], s[3]));
}

// sim_c row softmax of (rowmax(E) - E) over d; E f32 [b][256][256]
__global__ void simc_kernel(const float* __restrict__ E, u16* __restrict__ simc)
{
    int bb = blockIdx.y;
    const float* Eb = E + bb * 65536;
    u16* sc = simc + bb * 65536;
    int c = blockIdx.x, d = threadIdx.x;
    float e = Eb[c * 256 + d];
    float rmax = blockReduce(e, 0);
    float v = rmax - e;
    float vmax = blockReduce(v, 0);
    float p = __expf(v - vmax);
    float s = blockReduce(p, 1);
    sc[c * 256 + d] = f2h_u(p / s);
}

extern "C" void kernel_launch(void* const* d_in, const int* in_sizes, int n_in,
                              void* d_out, int out_size, void* d_ws, size_t ws_size,
                              hipStream_t stream)
{
    const float* x      = (const float*)d_in[0];
    const float* xth    = (const float*)d_in[1];
    const float* Wk_rgb = (const float*)d_in[2];
    const float* bk_rgb = (const float*)d_in[3];
    const float* Wk_th  = (const float*)d_in[4];
    const float* bk_th  = (const float*)d_in[5];
    const float* Wv_rgb = (const float*)d_in[6];
    const float* bv_rgb = (const float*)d_in[7];
    const float* Wv_th  = (const float*)d_in[8];
    const float* bv_th  = (const float*)d_in[9];
    const float* g1r = (const float*)d_in[10];
    const float* g1t = (const float*)d_in[11];
    const float* g2r = (const float*)d_in[12];
    const float* g2t = (const float*)d_in[13];

    // ws carve-up (~176.5 MB)
    u16* wts   = (u16*)d_ws;             // [4][256][256] fp16
    u16* Kt    = wts + 4 * 65536;        // [4][4096][256] x_k^T  (dead after St GEMM)
    u16* Ktth  = Kt + 4 * CN;
    u16* Vt2   = Ktth + 4 * CN;          // [4][2][4096][256] (t=0: x_v^T, 1: x_v_th^T)
    u16* V2    = Vt2 + 8 * CN;           // [4][2][256][4096]
    u16* StH   = V2 + 8 * CN;            // [4][4096][4096] fp16 St -> Pt in place (128 MB)
    // small buffers alias the dead-after-St Kt region (written post-St only)
    u16* simc   = Kt;                    // [4][256][256] fp16
    float* E    = (float*)(Kt + 4 * 65536);  // [4][256][256] f32
    u16* xT    = StH;                    // alias: dead before first StH write
    u16* xthT  = xT + 4 * CN;

    float* outX2  = (float*)d_out;
    float* outXt2 = outX2 + 4 * CN;

    // softmax stats live in d_out scratch (dead until PV writes d_out):
    // pmax [4][32][4096], psum [4][32][4096], cmax/crcp [4][4096]
    float* pmax = outX2;
    float* psum = pmax + 4 * 32 * 4096;
    float* cmax = psum + 4 * 32 * 4096;
    float* crcp = cmax + 4 * 4096;

    cvt_w_kernel<<<1024, 256, 0, stream>>>(Wk_rgb, Wk_th, Wv_rgb, Wv_th, wts);
    tr_f32_h2<<<dim3(64, 4, 8), 256, 0, stream>>>(x, xth, xT, xthT);

    // all 16 projections, one dispatch (1024 blocks, 2/CU)
    proj_all<<<dim3(2, 32, 16), 256, 0, stream>>>(xT, xthT, wts,
        bk_rgb, bk_th, bv_rgb, bv_th, Kt, Ktth, Vt2, Vt2 + CN);

    tr_h_h<<<dim3(4, 64, 8), 256, 0, stream>>>(Vt2, V2, 4096, 256, CN, CN);

    // St[b][m][n] = Kt[b][m][.] . Ktth[b][n][.]  + fused column stats
    st_gemm<<<4096, 256, 0, stream>>>(Kt, Ktth, StH, pmax, psum);
    stats_combine<<<dim3(16, 4), 256, 0, stream>>>(pmax, psum, cmax, crcp);
    pt8_kernel<<<dim3(2, 4096, 4), 256, 0, stream>>>(StH, cmax, crcp);

    // x_1 = gamma1 * (V @ P) + x   (flat 512 blocks, XCD-swizzled)
    gemm_fused<0><<<512, 256, 0, stream>>>(
        V2, StH, g1r, g1t, x, xth, outX2, outXt2);

    // energy[c,d] = sum_n Vth[c,n] V[d,n]; split-K (32 slices of 128) x 4 batches
    (void)hipMemsetAsync(E, 0, 4 * 65536 * sizeof(float), stream);
    gemm512<2><<<dim3(2, 2, 128), 256, 0, stream>>>(
        V2 + CN, 4096, 2 * CN, V2, 4096, 2 * CN,
        4096, 128, 5, E, 256, 65536);
    simc_kernel<<<dim3(256, 4), 256, 0, stream>>>(E, simc);

    // x_2 = gamma2 * (simc @ V) + x_1   (in-place on d_out, flat 512 blocks)
    gemm_fused<1><<<512, 256, 0, stream>>>(
        simc, Vt2, g2r, g2t, outX2, outXt2, outX2, outXt2);
}